// Round 2
// baseline (3662.774 us; speedup 1.0000x reference)
//
#include <hip/hip_runtime.h>
#include <hip/hip_bf16.h>

// Problem constants
#define B_    16
#define H_    768
#define W_    768
#define HW_   (H_*W_)        // 589824
#define P_    64
#define NP_   4
#define TOPK_ 100
#define NPATCH (B_*NP_)      // 64 patches

// ---------------------------------------------------------------------------
// zero the histogram/counter region
// ---------------------------------------------------------------------------
__global__ void k_zero(unsigned* __restrict__ p, int n){
  int i = blockIdx.x*blockDim.x + threadIdx.x;
  if (i < n) p[i] = 0u;
}

// ---------------------------------------------------------------------------
// flag = any(source < 0)
// ---------------------------------------------------------------------------
__global__ void k_flag(const float4* __restrict__ s, int n4, int* __restrict__ flag){
  int idx = blockIdx.x*blockDim.x + threadIdx.x;
  int strd = gridDim.x*blockDim.x;
  bool neg = false;
  for (int i=idx; i<n4; i+=strd){
    float4 q = s[i];
    neg = neg || (q.x<0.f) || (q.y<0.f) || (q.z<0.f) || (q.w<0.f);
  }
  if (__any((int)neg)){
    if ((threadIdx.x & 63) == 0) atomicOr(flag, 1);
  }
}

// ---------------------------------------------------------------------------
// detector: mask = sigmoid(20*(brightness-0.65)) * sigmoid(20*(0.15-sat))
// ---------------------------------------------------------------------------
__global__ void k_detector(const float* __restrict__ src, const int* __restrict__ flag,
                           float* __restrict__ mask){
  int i = blockIdx.x*blockDim.x + threadIdx.x;
  if (i >= B_*HW_) return;
  int b = i / HW_;
  int p = i - b*HW_;
  const float* sb = src + (size_t)b*3*HW_;
  float r = sb[p], g = sb[HW_+p], bl = sb[2*HW_+p];
  if (*flag){ r = (r+1.f)*0.5f; g = (g+1.f)*0.5f; bl = (bl+1.f)*0.5f; }
  float br = 0.299f*r + 0.587f*g + 0.114f*bl;
  float bm = 1.f/(1.f + expf(-20.f*(br - 0.65f)));
  float mx = fmaxf(r, fmaxf(g, bl));
  float mn = fminf(r, fminf(g, bl));
  float ls = 1.f/(1.f + expf(-20.f*(0.15f - (mx-mn))));
  mask[i] = bm*ls;
}

// ---------------------------------------------------------------------------
// separable 15x15 box filter (zero pad, divide by 225 at the end)
// ---------------------------------------------------------------------------
__global__ void k_box_row(const float* __restrict__ in, float* __restrict__ out){
  int i = blockIdx.x*blockDim.x + threadIdx.x;
  if (i >= B_*HW_) return;
  int x = i % W_;
  int base = i - x;
  float s = 0.f;
  #pragma unroll
  for (int d=-7; d<=7; ++d){
    int xx = x + d;
    if (xx >= 0 && xx < W_) s += in[base + xx];
  }
  out[i] = s;
}

__global__ void k_box_col(const float* __restrict__ in, float* __restrict__ out){
  int i = blockIdx.x*blockDim.x + threadIdx.x;
  if (i >= B_*HW_) return;
  int p = i % HW_;
  int y = p / W_;
  float s = 0.f;
  #pragma unroll
  for (int d=-7; d<=7; ++d){
    int yy = y + d;
    if (yy >= 0 && yy < H_) s += in[i + d*W_];
  }
  out[i] = s / 225.0f;
}

// ---------------------------------------------------------------------------
// TOP-K, stage 1: per-image 2048-bin histogram of valbits>>19
// (window values are in [0,1] -> bits < 0x3F800001 -> bin < 2048)
// wave match-aggregated atomics: one atomicAdd per distinct bin per wave
// ---------------------------------------------------------------------------
__global__ __launch_bounds__(256) void k_hist(const float* __restrict__ win,
                                              unsigned* __restrict__ hist){
  const int img   = blockIdx.x >> 6;
  const int chunk = blockIdx.x & 63;
  const float4* base = reinterpret_cast<const float4*>(win + (size_t)img*HW_ + chunk*9216);
  unsigned* h = hist + img*2048;
  const int lane = threadIdx.x & 63;
  for (int it=0; it<9; ++it){
    float4 q = base[it*256 + threadIdx.x];
    float vv[4] = {q.x, q.y, q.z, q.w};
    #pragma unroll
    for (int c=0;c<4;c++){
      unsigned bin = __float_as_uint(vv[c]) >> 19;
      unsigned long long rem = __ballot(true);
      while (rem){
        int leader = __builtin_ctzll(rem);
        unsigned lbin = __shfl(bin, leader);
        unsigned long long grp = __ballot(bin == lbin) & rem;
        if (lane == leader) atomicAdd(&h[lbin], (unsigned)__popcll(grp));
        rem &= ~grp;
      }
    }
  }
}

// ---------------------------------------------------------------------------
// TOP-K, stage 2: find threshold bin t1 + count strictly above it
// ---------------------------------------------------------------------------
__global__ __launch_bounds__(256) void k_thresh_a(const unsigned* __restrict__ hist,
                                                  int2* __restrict__ tinfo){
  const int img = blockIdx.x;
  __shared__ unsigned h[2048];
  __shared__ unsigned ch[256];
  const int t = threadIdx.x;
  for (int i=t;i<2048;i+=256) h[i] = hist[img*2048+i];
  __syncthreads();
  unsigned s = 0;
  #pragma unroll
  for (int j=0;j<8;j++) s += h[t*8+j];
  ch[t] = s;
  __syncthreads();
  if (t==0){
    unsigned acc = 0; int c = 255;
    for (; c>0; --c){ if (acc + ch[c] >= (unsigned)TOPK_) break; acc += ch[c]; }
    int b = c*8+7;
    for (; b>c*8; --b){ if (acc + h[b] >= (unsigned)TOPK_) break; acc += h[b]; }
    tinfo[img] = make_int2(b, (int)acc);
  }
}

// ---------------------------------------------------------------------------
// TOP-K, stage 3: 8192-bin histogram of bits 18..6 for elements in bin t1
// ---------------------------------------------------------------------------
__global__ __launch_bounds__(256) void k_hist2(const float* __restrict__ win,
                                               const int2* __restrict__ tinfo,
                                               unsigned* __restrict__ hist2){
  const int img   = blockIdx.x >> 6;
  const int chunk = blockIdx.x & 63;
  const unsigned t1 = (unsigned)tinfo[img].x;
  const float4* base = reinterpret_cast<const float4*>(win + (size_t)img*HW_ + chunk*9216);
  unsigned* h = hist2 + img*8192;
  const int lane = threadIdx.x & 63;
  for (int it=0; it<9; ++it){
    float4 q = base[it*256 + threadIdx.x];
    float vv[4] = {q.x, q.y, q.z, q.w};
    #pragma unroll
    for (int c=0;c<4;c++){
      unsigned vb = __float_as_uint(vv[c]);
      bool act = ((vb >> 19) == t1);
      unsigned sub = (vb >> 6) & 8191u;
      unsigned long long rem = __ballot(act);
      while (rem){
        int leader = __builtin_ctzll(rem);
        unsigned ls = __shfl(sub, leader);
        unsigned long long grp = __ballot(act && sub == ls) & rem;
        if (lane == leader) atomicAdd(&h[ls], (unsigned)__popcll(grp));
        rem &= ~grp;
      }
    }
  }
}

// ---------------------------------------------------------------------------
// TOP-K, stage 4: final 26-bit threshold T
// ---------------------------------------------------------------------------
__global__ __launch_bounds__(256) void k_thresh_b(const unsigned* __restrict__ hist2,
                                                  const int2* __restrict__ tinfo,
                                                  unsigned* __restrict__ thr){
  const int img = blockIdx.x;
  __shared__ unsigned h[8192];
  __shared__ unsigned ch[256];
  const int t = threadIdx.x;
  for (int i=t;i<8192;i+=256) h[i] = hist2[img*8192+i];
  __syncthreads();
  unsigned s = 0;
  #pragma unroll
  for (int j=0;j<32;j++) s += h[t*32+j];
  ch[t] = s;
  __syncthreads();
  if (t==0){
    unsigned acc = (unsigned)tinfo[img].y;
    int c = 255;
    for (; c>0; --c){ if (acc + ch[c] >= (unsigned)TOPK_) break; acc += ch[c]; }
    int b = c*32+31;
    for (; b>c*32; --b){ if (acc + h[b] >= (unsigned)TOPK_) break; acc += h[b]; }
    thr[img] = (((unsigned)tinfo[img].x) << 19) | ((unsigned)b << 6);
  }
}

// ---------------------------------------------------------------------------
// TOP-K, stage 5: compact all elements with valbits >= T into 64-bit keys
// key = (valbits<<32) | ~idx  -> descending key order == (value desc, idx asc)
// ---------------------------------------------------------------------------
__global__ __launch_bounds__(256) void k_collect(const float* __restrict__ win,
                                                 const unsigned* __restrict__ thr,
                                                 unsigned long long* __restrict__ cand,
                                                 unsigned* __restrict__ cnt){
  const int img   = blockIdx.x >> 6;
  const int chunk = blockIdx.x & 63;
  const unsigned T = thr[img];
  const float4* base = reinterpret_cast<const float4*>(win + (size_t)img*HW_ + chunk*9216);
  unsigned long long* cimg = cand + (size_t)img*2048;
  const int lane = threadIdx.x & 63;
  for (int it=0; it<9; ++it){
    float4 q = base[it*256 + threadIdx.x];
    float vv[4] = {q.x, q.y, q.z, q.w};
    #pragma unroll
    for (int c=0;c<4;c++){
      unsigned vb = __float_as_uint(vv[c]);
      bool take = (vb >= T);
      unsigned long long m = __ballot(take);
      if (m){
        int leader = __builtin_ctzll(m);
        unsigned bs = 0;
        if (lane == leader) bs = atomicAdd(&cnt[img], (unsigned)__popcll(m));
        bs = __shfl(bs, leader);
        if (take){
          unsigned off  = (unsigned)__popcll(m & ((1ULL << lane) - 1ULL));
          unsigned slot = bs + off;
          if (slot < 2048u){
            unsigned idx = (unsigned)(chunk*9216 + (it*256 + threadIdx.x)*4 + c);
            cimg[slot] = (((unsigned long long)vb) << 32) | (unsigned)(~idx);
          }
        }
      }
    }
  }
}

// ---------------------------------------------------------------------------
// TOP-K, stage 6: bitonic sort (ascending) of up to 2048 keys; best = s[2047].
// Emits the 4 selected patch coords per image.
// ---------------------------------------------------------------------------
__global__ __launch_bounds__(1024) void k_sort(const unsigned long long* __restrict__ cand,
                                               const unsigned* __restrict__ cnt,
                                               const int* __restrict__ rand_sel,
                                               int* __restrict__ coords){
  const int img = blockIdx.x;
  __shared__ unsigned long long s[2048];
  const int t = threadIdx.x;
  unsigned M = cnt[img]; if (M > 2048u) M = 2048u;
  s[t]        = (t          < (int)M) ? cand[(size_t)img*2048 + t]        : 0ULL;
  s[t+1024]   = (t+1024     < (int)M) ? cand[(size_t)img*2048 + t + 1024] : 0ULL;
  for (unsigned k=2; k<=2048u; k<<=1){
    for (unsigned j=k>>1; j>0; j>>=1){
      __syncthreads();
      unsigned i = (((unsigned)t & ~(j-1u)) << 1) | ((unsigned)t & (j-1u));
      unsigned l = i | j;
      unsigned long long a = s[i], b = s[l];
      bool up = ((i & k) == 0u);
      if ((a > b) == up){ s[i] = b; s[l] = a; }
    }
  }
  __syncthreads();
  if (t < NP_){
    int rs = rand_sel[img*NP_ + t];
    rs = rs<0?0:(rs>99?99:rs);
    unsigned long long key = s[2047 - rs];
    unsigned idx = ~((unsigned)(key & 0xFFFFFFFFull));
    int rr = (int)(idx / (unsigned)W_);
    int cc = (int)(idx % (unsigned)W_);
    int y = rr - P_/2; y = y<0?0:(y>(H_-P_)?(H_-P_):y);
    int x = cc - P_/2; x = x<0?0:(x>(W_-P_)?(W_-P_):x);
    coords[(img*NP_+t)*2]   = y;
    coords[(img*NP_+t)*2+1] = x;
  }
}

// ---------------------------------------------------------------------------
// gather 64 patches of (3,64,64) from pred
// ---------------------------------------------------------------------------
__global__ void k_patch(const float* __restrict__ pred, const int* __restrict__ coords,
                        float* __restrict__ patches){
  int i = blockIdx.x*blockDim.x + threadIdx.x;
  if (i >= NPATCH*3*P_*P_) return;
  int x  = i & 63;
  int y  = (i >> 6) & 63;
  int c  = (i >> 12) % 3;
  int bp = i / (3*P_*P_);
  int b  = bp >> 2;
  int py = coords[bp*2], px = coords[bp*2+1];
  patches[i] = pred[(((size_t)b*3 + c)*H_ + (py+y))*W_ + (px+x)];
}

// ---------------------------------------------------------------------------
// conv1: 3->64, 64x64 -> 32x32, k4 s2 p1, + bias + leaky_relu(0.2) at store
// ---------------------------------------------------------------------------
__global__ __launch_bounds__(256) void k_conv1(const float* __restrict__ in,
    const float* __restrict__ w, const float* __restrict__ bias, float* __restrict__ out){
  int id = blockIdx.x*256 + threadIdx.x;
  if (id >= NPATCH*64*32) return;
  const int oy = id % 32;
  const int co = (id/32) % 64;
  const int n  = id / (32*64);
  float acc[32];
  #pragma unroll
  for (int o=0;o<32;o++) acc[o]=0.f;
  const float* inN = in + (size_t)n*3*64*64;
  #pragma unroll
  for (int ci=0;ci<3;ci++){
    #pragma unroll
    for (int ky=0;ky<4;ky++){
      const int iy = oy*2 - 1 + ky;
      if (iy < 0 || iy >= 64) continue;
      float raw[64];
      const float4* rp = reinterpret_cast<const float4*>(inN + ci*4096 + iy*64);
      #pragma unroll
      for (int j=0;j<16;j++){ float4 q=rp[j]; raw[4*j]=q.x; raw[4*j+1]=q.y; raw[4*j+2]=q.z; raw[4*j+3]=q.w; }
      const float4 wq = *reinterpret_cast<const float4*>(w + ((co*3+ci)*4+ky)*4);
      const float wk[4] = {wq.x, wq.y, wq.z, wq.w};
      #pragma unroll
      for (int kx=0;kx<4;kx++){
        #pragma unroll
        for (int ox=0;ox<32;ox++){
          const int ix = ox*2 - 1 + kx;
          if (ix >= 0 && ix < 64) acc[ox] += raw[ix]*wk[kx];
        }
      }
    }
  }
  const float bv = bias[co];
  #pragma unroll
  for (int ox=0;ox<32;ox++){
    float u = acc[ox] + bv;
    out[(((size_t)n*64 + co)*32 + oy)*32 + ox] = u > 0.f ? u : 0.2f*u;
  }
}

// ---------------------------------------------------------------------------
// generic s2/p1 k4 conv for layers 2..4, optional BN+lrelu applied to INPUT
// ---------------------------------------------------------------------------
template<int CI, int CO, int HI, bool BN_IN>
__global__ __launch_bounds__(256) void k_conv_s2(const float* __restrict__ in,
    const float* __restrict__ w, const float* __restrict__ bias,
    const float* __restrict__ scale, const float* __restrict__ shift,
    float* __restrict__ out){
  constexpr int HO = HI/2, WI = HI, WO = HI/2, NCOG = CO/2;
  int id = blockIdx.x*256 + threadIdx.x;
  if (id >= NPATCH*NCOG*HO) return;
  const int oy  = id % HO;
  const int cog = (id/HO) % NCOG;
  const int n   = id / (HO*NCOG);
  const int co0 = cog*2;
  float acc[2][WO];
  #pragma unroll
  for (int a=0;a<2;a++){
    #pragma unroll
    for (int o=0;o<WO;o++) acc[a][o]=0.f;
  }
  const float* inN = in + (size_t)n*CI*HI*WI;
  for (int ci=0; ci<CI; ++ci){
    float sc = 1.f, sh = 0.f;
    if constexpr (BN_IN){ sc = scale[ci]; sh = shift[ci]; }
    const float* inC = inN + ci*HI*WI;
    #pragma unroll
    for (int ky=0;ky<4;ky++){
      const int iy = oy*2 - 1 + ky;
      if (iy < 0 || iy >= HI) continue;
      float raw[WI];
      const float4* rp = reinterpret_cast<const float4*>(inC + iy*WI);
      #pragma unroll
      for (int j=0;j<WI/4;j++){ float4 q=rp[j]; raw[4*j]=q.x; raw[4*j+1]=q.y; raw[4*j+2]=q.z; raw[4*j+3]=q.w; }
      if constexpr (BN_IN){
        #pragma unroll
        for (int j=0;j<WI;j++){ float x = raw[j]*sc + sh; raw[j] = x > 0.f ? x : 0.2f*x; }
      }
      #pragma unroll
      for (int c2=0;c2<2;c2++){
        const float4 wq = *reinterpret_cast<const float4*>(w + (((size_t)(co0+c2)*CI + ci)*4 + ky)*4);
        const float wk[4] = {wq.x, wq.y, wq.z, wq.w};
        #pragma unroll
        for (int kx=0;kx<4;kx++){
          #pragma unroll
          for (int ox=0;ox<WO;ox++){
            const int ix = ox*2 - 1 + kx;
            if (ix >= 0 && ix < WI) acc[c2][ox] += raw[ix]*wk[kx];
          }
        }
      }
    }
  }
  #pragma unroll
  for (int c2=0;c2<2;c2++){
    const float bv = bias[co0+c2];
    #pragma unroll
    for (int ox=0;ox<WO;ox++){
      out[(((size_t)n*CO + co0+c2)*HO + oy)*WO + ox] = acc[c2][ox] + bv;
    }
  }
}

// ---------------------------------------------------------------------------
// training-mode BN statistics -> per-channel scale/shift
// ---------------------------------------------------------------------------
template<int CO, int PX>
__global__ __launch_bounds__(256) void k_bnstats(const float* __restrict__ z,
    const float* __restrict__ g, const float* __restrict__ be,
    float* __restrict__ scale, float* __restrict__ shift){
  const int c = blockIdx.x, t = threadIdx.x;
  double s = 0.0, q = 0.0;
  for (int i=t; i<NPATCH*PX; i+=256){
    const int n = i / PX, p = i % PX;
    const float x = z[((size_t)n*CO + c)*PX + p];
    s += (double)x; q += (double)x*(double)x;
  }
  #pragma unroll
  for (int o=32;o>=1;o>>=1){ s += __shfl_down(s,o); q += __shfl_down(q,o); }
  __shared__ double ls[4], lq[4];
  if ((t & 63) == 0){ ls[t>>6] = s; lq[t>>6] = q; }
  __syncthreads();
  if (t==0){
    const double S = ls[0]+ls[1]+ls[2]+ls[3];
    const double Q = lq[0]+lq[1]+lq[2]+lq[3];
    const double cnt = (double)(NPATCH*PX);
    const double m  = S/cnt;
    const double var = Q/cnt - m*m;
    const float scl = g[c] / sqrtf((float)var + 1e-5f);
    scale[c] = scl;
    shift[c] = be[c] - (float)m*scl;
  }
}

// ---------------------------------------------------------------------------
// conv5: 512 -> 1, 4x4 input, k4 s1 p0 (dot product), BN4+lrelu on input
// ---------------------------------------------------------------------------
__global__ __launch_bounds__(256) void k_conv5(const float* __restrict__ z4,
    const float* __restrict__ scale, const float* __restrict__ shift,
    const float* __restrict__ w5, const float* __restrict__ b5,
    float* __restrict__ logits){
  const int n = blockIdx.x, t = threadIdx.x;
  float part = 0.f;
  for (int k=t; k<8192; k+=256){
    const int ci = k >> 4;
    float x = z4[((size_t)n*512)*16 + k];
    x = x*scale[ci] + shift[ci];
    x = x > 0.f ? x : 0.2f*x;
    part += x * w5[k];
  }
  #pragma unroll
  for (int o=32;o>=1;o>>=1) part += __shfl_down(part, o);
  __shared__ float ls[4];
  if ((t & 63) == 0) ls[t>>6] = part;
  __syncthreads();
  if (t==0) logits[n] = ls[0]+ls[1]+ls[2]+ls[3] + b5[0];
}

// ---------------------------------------------------------------------------
// loss = mean(softplus(-logit)) over 64 patches
// ---------------------------------------------------------------------------
__global__ void k_loss(const float* __restrict__ logits, float* __restrict__ out){
  const int t = threadIdx.x;
  float u  = -logits[t];
  float sp = fmaxf(u, 0.f) + log1pf(expf(-fabsf(u)));
  #pragma unroll
  for (int o=32;o>=1;o>>=1) sp += __shfl_down(sp, o);
  if (t==0) out[0] = sp * (1.0f/64.0f);
}

// ---------------------------------------------------------------------------
extern "C" void kernel_launch(void* const* d_in, const int* in_sizes, int n_in,
                              void* d_out, int out_size, void* d_ws, size_t ws_size,
                              hipStream_t stream) {
  const float* pred     = (const float*)d_in[0];
  const float* source   = (const float*)d_in[1];
  const int*   rand_sel = (const int*)  d_in[2];
  const float* w1 = (const float*)d_in[3];  const float* b1 = (const float*)d_in[4];
  const float* w2 = (const float*)d_in[5];  const float* b2 = (const float*)d_in[6];
  const float* g2 = (const float*)d_in[7];  const float* be2= (const float*)d_in[8];
  const float* w3 = (const float*)d_in[9];  const float* b3 = (const float*)d_in[10];
  const float* g3 = (const float*)d_in[11]; const float* be3= (const float*)d_in[12];
  const float* w4 = (const float*)d_in[13]; const float* b4 = (const float*)d_in[14];
  const float* g4 = (const float*)d_in[15]; const float* be4= (const float*)d_in[16];
  const float* w5 = (const float*)d_in[17]; const float* b5 = (const float*)d_in[18];

  float* ws = (float*)d_ws;
  // --- zero-initialized region (contiguous) ---
  unsigned* hist  = (unsigned*)ws;          // 16*2048
  unsigned* hist2 = hist + 16*2048;         // 16*8192
  unsigned* cntb  = hist2 + 16*8192;        // 16
  int*      flag  = (int*)(cntb + 16);      // 16
  const int ZTOT  = 16*2048 + 16*8192 + 16 + 16;   // u32 count
  size_t o = (size_t)ZTOT;
  int2*     tinfo = (int2*)(ws + o);        o += 32;
  unsigned* thr   = (unsigned*)(ws + o);    o += 16;
  // o is even here -> 8-byte aligned for cand
  unsigned long long* cand = (unsigned long long*)(ws + o); o += (size_t)16*2048*2;
  float* maskbuf = ws + o;              o += (size_t)B_*HW_;   // mask, later window
  float* rowsum  = ws + o;              o += (size_t)B_*HW_;
  int*   coords  = (int*)(ws + o);      o += 128;
  float* patches = ws + o;              o += (size_t)NPATCH*3*64*64;
  float* a1      = ws + o;              o += (size_t)NPATCH*64*32*32;
  float* z2      = ws + o;              o += (size_t)NPATCH*128*16*16;
  float* z3      = ws + o;              o += (size_t)NPATCH*256*8*8;
  float* z4      = ws + o;              o += (size_t)NPATCH*512*4*4;
  float* scale2  = ws + o;              o += 128;
  float* shift2  = ws + o;              o += 128;
  float* scale3  = ws + o;              o += 256;
  float* shift3  = ws + o;              o += 256;
  float* scale4  = ws + o;              o += 512;
  float* shift4  = ws + o;              o += 512;
  float* logits  = ws + o;              o += 64;
  (void)ws_size; (void)in_sizes; (void)n_in; (void)out_size;

  const int npix = B_*HW_;
  const int pixBlocks = (npix + 255)/256;

  k_zero<<<(ZTOT + 255)/256, 256, 0, stream>>>(hist, ZTOT);
  k_flag<<<2048, 256, 0, stream>>>((const float4*)source, (B_*3*HW_)/4, flag);
  k_detector<<<pixBlocks, 256, 0, stream>>>(source, flag, maskbuf);
  k_box_row<<<pixBlocks, 256, 0, stream>>>(maskbuf, rowsum);
  k_box_col<<<pixBlocks, 256, 0, stream>>>(rowsum, maskbuf);   // window overwrites mask

  k_hist   <<<16*64, 256, 0, stream>>>(maskbuf, hist);
  k_thresh_a<<<16, 256, 0, stream>>>(hist, tinfo);
  k_hist2  <<<16*64, 256, 0, stream>>>(maskbuf, tinfo, hist2);
  k_thresh_b<<<16, 256, 0, stream>>>(hist2, tinfo, thr);
  k_collect<<<16*64, 256, 0, stream>>>(maskbuf, thr, cand, cntb);
  k_sort   <<<16, 1024, 0, stream>>>(cand, cntb, rand_sel, coords);

  k_patch<<<(NPATCH*3*64*64 + 255)/256, 256, 0, stream>>>(pred, coords, patches);

  k_conv1<<<(NPATCH*64*32 + 255)/256, 256, 0, stream>>>(patches, w1, b1, a1);

  k_conv_s2<64, 128, 32, false><<<(NPATCH*64*16 + 255)/256, 256, 0, stream>>>(
      a1, w2, b2, nullptr, nullptr, z2);
  k_bnstats<128, 256><<<128, 256, 0, stream>>>(z2, g2, be2, scale2, shift2);

  k_conv_s2<128, 256, 16, true><<<(NPATCH*128*8 + 255)/256, 256, 0, stream>>>(
      z2, w3, b3, scale2, shift2, z3);
  k_bnstats<256, 64><<<256, 256, 0, stream>>>(z3, g3, be3, scale3, shift3);

  k_conv_s2<256, 512, 8, true><<<(NPATCH*256*4 + 255)/256, 256, 0, stream>>>(
      z3, w4, b4, scale3, shift3, z4);
  k_bnstats<512, 16><<<512, 256, 0, stream>>>(z4, g4, be4, scale4, shift4);

  k_conv5<<<NPATCH, 256, 0, stream>>>(z4, scale4, shift4, w5, b5, logits);
  k_loss<<<1, 64, 0, stream>>>(logits, (float*)d_out);
}

// Round 3
// 1936.476 us; speedup vs baseline: 1.8915x; 1.8915x over previous
//
#include <hip/hip_runtime.h>
#include <hip/hip_bf16.h>

// Problem constants
#define B_    16
#define H_    768
#define W_    768
#define HW_   (H_*W_)        // 589824
#define P_    64
#define NP_   4
#define TOPK_ 100
#define NPATCH (B_*NP_)      // 64 patches

// ---------------------------------------------------------------------------
// zero the histogram/counter region
// ---------------------------------------------------------------------------
__global__ void k_zero(unsigned* __restrict__ p, int n){
  int i = blockIdx.x*blockDim.x + threadIdx.x;
  if (i < n) p[i] = 0u;
}

// ---------------------------------------------------------------------------
// flag = any(source < 0)
// ---------------------------------------------------------------------------
__global__ void k_flag(const float4* __restrict__ s, int n4, int* __restrict__ flag){
  int idx = blockIdx.x*blockDim.x + threadIdx.x;
  int strd = gridDim.x*blockDim.x;
  bool neg = false;
  for (int i=idx; i<n4; i+=strd){
    float4 q = s[i];
    neg = neg || (q.x<0.f) || (q.y<0.f) || (q.z<0.f) || (q.w<0.f);
  }
  if (__any((int)neg)){
    if ((threadIdx.x & 63) == 0) atomicOr(flag, 1);
  }
}

// ---------------------------------------------------------------------------
// detector: mask = sigmoid(20*(brightness-0.65)) * sigmoid(20*(0.15-sat))
// ---------------------------------------------------------------------------
__global__ void k_detector(const float* __restrict__ src, const int* __restrict__ flag,
                           float* __restrict__ mask){
  int i = blockIdx.x*blockDim.x + threadIdx.x;
  if (i >= B_*HW_) return;
  int b = i / HW_;
  int p = i - b*HW_;
  const float* sb = src + (size_t)b*3*HW_;
  float r = sb[p], g = sb[HW_+p], bl = sb[2*HW_+p];
  if (*flag){ r = (r+1.f)*0.5f; g = (g+1.f)*0.5f; bl = (bl+1.f)*0.5f; }
  float br = 0.299f*r + 0.587f*g + 0.114f*bl;
  float bm = 1.f/(1.f + expf(-20.f*(br - 0.65f)));
  float mx = fmaxf(r, fmaxf(g, bl));
  float mn = fminf(r, fminf(g, bl));
  float ls = 1.f/(1.f + expf(-20.f*(0.15f - (mx-mn))));
  mask[i] = bm*ls;
}

// ---------------------------------------------------------------------------
// separable 15x15 box filter (zero pad, divide by 225 at the end)
// ---------------------------------------------------------------------------
__global__ void k_box_row(const float* __restrict__ in, float* __restrict__ out){
  int i = blockIdx.x*blockDim.x + threadIdx.x;
  if (i >= B_*HW_) return;
  int x = i % W_;
  int base = i - x;
  float s = 0.f;
  #pragma unroll
  for (int d=-7; d<=7; ++d){
    int xx = x + d;
    if (xx >= 0 && xx < W_) s += in[base + xx];
  }
  out[i] = s;
}

__global__ void k_box_col(const float* __restrict__ in, float* __restrict__ out){
  int i = blockIdx.x*blockDim.x + threadIdx.x;
  if (i >= B_*HW_) return;
  int p = i % HW_;
  int y = p / W_;
  float s = 0.f;
  #pragma unroll
  for (int d=-7; d<=7; ++d){
    int yy = y + d;
    if (yy >= 0 && yy < H_) s += in[i + d*W_];
  }
  out[i] = s / 225.0f;
}

// ---------------------------------------------------------------------------
// TOP-K stage 1: per-image 2048-bin histogram of valbits>>19.
// LDS-privatized per block (16 chunk-blocks per image), sparse global flush.
// ---------------------------------------------------------------------------
__global__ __launch_bounds__(256) void k_hist(const float* __restrict__ win,
                                              unsigned* __restrict__ hist){
  const int img   = blockIdx.x >> 4;
  const int chunk = blockIdx.x & 15;
  __shared__ unsigned lh[2048];
  for (int i=threadIdx.x;i<2048;i+=256) lh[i]=0u;
  __syncthreads();
  const float4* base = reinterpret_cast<const float4*>(win + (size_t)img*HW_ + chunk*36864);
  for (int it=0; it<36; ++it){
    float4 q = base[it*256 + threadIdx.x];
    atomicAdd(&lh[__float_as_uint(q.x) >> 19], 1u);
    atomicAdd(&lh[__float_as_uint(q.y) >> 19], 1u);
    atomicAdd(&lh[__float_as_uint(q.z) >> 19], 1u);
    atomicAdd(&lh[__float_as_uint(q.w) >> 19], 1u);
  }
  __syncthreads();
  unsigned* h = hist + img*2048;
  for (int i=threadIdx.x;i<2048;i+=256){
    unsigned v = lh[i];
    if (v) atomicAdd(&h[i], v);
  }
}

// ---------------------------------------------------------------------------
// TOP-K stage 2: find threshold bin t1 + count strictly above it
// ---------------------------------------------------------------------------
__global__ __launch_bounds__(256) void k_thresh_a(const unsigned* __restrict__ hist,
                                                  int2* __restrict__ tinfo){
  const int img = blockIdx.x;
  __shared__ unsigned h[2048];
  __shared__ unsigned ch[256];
  const int t = threadIdx.x;
  for (int i=t;i<2048;i+=256) h[i] = hist[img*2048+i];
  __syncthreads();
  unsigned s = 0;
  #pragma unroll
  for (int j=0;j<8;j++) s += h[t*8+j];
  ch[t] = s;
  __syncthreads();
  if (t==0){
    unsigned acc = 0; int c = 255;
    for (; c>0; --c){ if (acc + ch[c] >= (unsigned)TOPK_) break; acc += ch[c]; }
    int b = c*8+7;
    for (; b>c*8; --b){ if (acc + h[b] >= (unsigned)TOPK_) break; acc += h[b]; }
    tinfo[img] = make_int2(b, (int)acc);
  }
}

// ---------------------------------------------------------------------------
// TOP-K stage 3: 8192-bin histogram of bits 18..6 for elements in bin t1
// LDS-privatized, sparse flush.
// ---------------------------------------------------------------------------
__global__ __launch_bounds__(256) void k_hist2(const float* __restrict__ win,
                                               const int2* __restrict__ tinfo,
                                               unsigned* __restrict__ hist2){
  const int img   = blockIdx.x >> 4;
  const int chunk = blockIdx.x & 15;
  const unsigned t1 = (unsigned)tinfo[img].x;
  __shared__ unsigned lh[8192];
  for (int i=threadIdx.x;i<8192;i+=256) lh[i]=0u;
  __syncthreads();
  const float4* base = reinterpret_cast<const float4*>(win + (size_t)img*HW_ + chunk*36864);
  for (int it=0; it<36; ++it){
    float4 q = base[it*256 + threadIdx.x];
    float vv[4] = {q.x, q.y, q.z, q.w};
    #pragma unroll
    for (int c=0;c<4;c++){
      unsigned vb = __float_as_uint(vv[c]);
      if ((vb >> 19) == t1) atomicAdd(&lh[(vb >> 6) & 8191u], 1u);
    }
  }
  __syncthreads();
  unsigned* h = hist2 + img*8192;
  for (int i=threadIdx.x;i<8192;i+=256){
    unsigned v = lh[i];
    if (v) atomicAdd(&h[i], v);
  }
}

// ---------------------------------------------------------------------------
// TOP-K stage 4: final 26-bit threshold T
// ---------------------------------------------------------------------------
__global__ __launch_bounds__(256) void k_thresh_b(const unsigned* __restrict__ hist2,
                                                  const int2* __restrict__ tinfo,
                                                  unsigned* __restrict__ thr){
  const int img = blockIdx.x;
  __shared__ unsigned h[8192];
  __shared__ unsigned ch[256];
  const int t = threadIdx.x;
  for (int i=t;i<8192;i+=256) h[i] = hist2[img*8192+i];
  __syncthreads();
  unsigned s = 0;
  #pragma unroll
  for (int j=0;j<32;j++) s += h[t*32+j];
  ch[t] = s;
  __syncthreads();
  if (t==0){
    unsigned acc = (unsigned)tinfo[img].y;
    int c = 255;
    for (; c>0; --c){ if (acc + ch[c] >= (unsigned)TOPK_) break; acc += ch[c]; }
    int b = c*32+31;
    for (; b>c*32; --b){ if (acc + h[b] >= (unsigned)TOPK_) break; acc += h[b]; }
    thr[img] = (((unsigned)tinfo[img].x) << 19) | ((unsigned)b << 6);
  }
}

// ---------------------------------------------------------------------------
// TOP-K stage 5: compact all elements with valbits >= T into 64-bit keys
// key = (valbits<<32) | ~idx  -> descending key order == (value desc, idx asc)
// ---------------------------------------------------------------------------
__global__ __launch_bounds__(256) void k_collect(const float* __restrict__ win,
                                                 const unsigned* __restrict__ thr,
                                                 unsigned long long* __restrict__ cand,
                                                 unsigned* __restrict__ cnt){
  const int img   = blockIdx.x >> 4;
  const int chunk = blockIdx.x & 15;
  const unsigned T = thr[img];
  const float4* base = reinterpret_cast<const float4*>(win + (size_t)img*HW_ + chunk*36864);
  unsigned long long* cimg = cand + (size_t)img*2048;
  const int lane = threadIdx.x & 63;
  for (int it=0; it<36; ++it){
    float4 q = base[it*256 + threadIdx.x];
    float vv[4] = {q.x, q.y, q.z, q.w};
    #pragma unroll
    for (int c=0;c<4;c++){
      unsigned vb = __float_as_uint(vv[c]);
      bool take = (vb >= T);
      unsigned long long m = __ballot(take);
      if (m){
        int leader = __builtin_ctzll(m);
        unsigned bs = 0;
        if (lane == leader) bs = atomicAdd(&cnt[img], (unsigned)__popcll(m));
        bs = __shfl(bs, leader);
        if (take){
          unsigned off  = (unsigned)__popcll(m & ((1ULL << lane) - 1ULL));
          unsigned slot = bs + off;
          if (slot < 2048u){
            unsigned idx = (unsigned)(chunk*36864 + (it*256 + threadIdx.x)*4 + c);
            cimg[slot] = (((unsigned long long)vb) << 32) | (unsigned)(~idx);
          }
        }
      }
    }
  }
}

// ---------------------------------------------------------------------------
// TOP-K stage 6: bitonic sort (ascending) of up to 2048 keys; best = s[2047].
// Emits the 4 selected patch coords per image.
// ---------------------------------------------------------------------------
__global__ __launch_bounds__(1024) void k_sort(const unsigned long long* __restrict__ cand,
                                               const unsigned* __restrict__ cnt,
                                               const int* __restrict__ rand_sel,
                                               int* __restrict__ coords){
  const int img = blockIdx.x;
  __shared__ unsigned long long s[2048];
  const int t = threadIdx.x;
  unsigned M = cnt[img]; if (M > 2048u) M = 2048u;
  s[t]        = (t          < (int)M) ? cand[(size_t)img*2048 + t]        : 0ULL;
  s[t+1024]   = (t+1024     < (int)M) ? cand[(size_t)img*2048 + t + 1024] : 0ULL;
  for (unsigned k=2; k<=2048u; k<<=1){
    for (unsigned j=k>>1; j>0; j>>=1){
      __syncthreads();
      unsigned i = (((unsigned)t & ~(j-1u)) << 1) | ((unsigned)t & (j-1u));
      unsigned l = i | j;
      unsigned long long a = s[i], b = s[l];
      bool up = ((i & k) == 0u);
      if ((a > b) == up){ s[i] = b; s[l] = a; }
    }
  }
  __syncthreads();
  if (t < NP_){
    int rs = rand_sel[img*NP_ + t];
    rs = rs<0?0:(rs>99?99:rs);
    unsigned long long key = s[2047 - rs];
    unsigned idx = ~((unsigned)(key & 0xFFFFFFFFull));
    int rr = (int)(idx / (unsigned)W_);
    int cc = (int)(idx % (unsigned)W_);
    int y = rr - P_/2; y = y<0?0:(y>(H_-P_)?(H_-P_):y);
    int x = cc - P_/2; x = x<0?0:(x>(W_-P_)?(W_-P_):x);
    coords[(img*NP_+t)*2]   = y;
    coords[(img*NP_+t)*2+1] = x;
  }
}

// ---------------------------------------------------------------------------
// gather 64 patches of (3,64,64) from pred
// ---------------------------------------------------------------------------
__global__ void k_patch(const float* __restrict__ pred, const int* __restrict__ coords,
                        float* __restrict__ patches){
  int i = blockIdx.x*blockDim.x + threadIdx.x;
  if (i >= NPATCH*3*P_*P_) return;
  int x  = i & 63;
  int y  = (i >> 6) & 63;
  int c  = (i >> 12) % 3;
  int bp = i / (3*P_*P_);
  int b  = bp >> 2;
  int py = coords[bp*2], px = coords[bp*2+1];
  patches[i] = pred[(((size_t)b*3 + c)*H_ + (py+y))*W_ + (px+x)];
}

// ---------------------------------------------------------------------------
// conv1: 3->64, 64x64 -> 32x32, k4 s2 p1, + bias + leaky_relu(0.2) at store
// ---------------------------------------------------------------------------
__global__ __launch_bounds__(256) void k_conv1(const float* __restrict__ in,
    const float* __restrict__ w, const float* __restrict__ bias, float* __restrict__ out){
  int id = blockIdx.x*256 + threadIdx.x;
  if (id >= NPATCH*64*32) return;
  const int oy = id % 32;
  const int co = (id/32) % 64;
  const int n  = id / (32*64);
  float acc[32];
  #pragma unroll
  for (int o=0;o<32;o++) acc[o]=0.f;
  const float* inN = in + (size_t)n*3*64*64;
  #pragma unroll
  for (int ci=0;ci<3;ci++){
    #pragma unroll
    for (int ky=0;ky<4;ky++){
      const int iy = oy*2 - 1 + ky;
      if (iy < 0 || iy >= 64) continue;
      float raw[64];
      const float4* rp = reinterpret_cast<const float4*>(inN + ci*4096 + iy*64);
      #pragma unroll
      for (int j=0;j<16;j++){ float4 q=rp[j]; raw[4*j]=q.x; raw[4*j+1]=q.y; raw[4*j+2]=q.z; raw[4*j+3]=q.w; }
      const float4 wq = *reinterpret_cast<const float4*>(w + ((co*3+ci)*4+ky)*4);
      const float wk[4] = {wq.x, wq.y, wq.z, wq.w};
      #pragma unroll
      for (int kx=0;kx<4;kx++){
        #pragma unroll
        for (int ox=0;ox<32;ox++){
          const int ix = ox*2 - 1 + kx;
          if (ix >= 0 && ix < 64) acc[ox] += raw[ix]*wk[kx];
        }
      }
    }
  }
  const float bv = bias[co];
  #pragma unroll
  for (int ox=0;ox<32;ox++){
    float u = acc[ox] + bv;
    out[(((size_t)n*64 + co)*32 + oy)*32 + ox] = u > 0.f ? u : 0.2f*u;
  }
}

// ---------------------------------------------------------------------------
// generic s2/p1 k4 conv for layers 2..4, optional BN+lrelu applied to INPUT.
// one thread per (n, co, oy) -> 512 blocks (2 waves/SIMD)
// ---------------------------------------------------------------------------
template<int CI, int CO, int HI, bool BN_IN>
__global__ __launch_bounds__(256) void k_conv_s2(const float* __restrict__ in,
    const float* __restrict__ w, const float* __restrict__ bias,
    const float* __restrict__ scale, const float* __restrict__ shift,
    float* __restrict__ out){
  constexpr int HO = HI/2, WI = HI, WO = HI/2;
  int id = blockIdx.x*256 + threadIdx.x;
  if (id >= NPATCH*CO*HO) return;
  const int oy = id % HO;
  const int co = (id/HO) % CO;
  const int n  = id / (HO*CO);
  float acc[WO];
  #pragma unroll
  for (int o=0;o<WO;o++) acc[o]=0.f;
  const float* inN = in + (size_t)n*CI*HI*WI;
  for (int ci=0; ci<CI; ++ci){
    float sc = 1.f, sh = 0.f;
    if constexpr (BN_IN){ sc = scale[ci]; sh = shift[ci]; }
    const float* inC = inN + ci*HI*WI;
    #pragma unroll
    for (int ky=0;ky<4;ky++){
      const int iy = oy*2 - 1 + ky;
      if (iy < 0 || iy >= HI) continue;
      float raw[WI];
      const float4* rp = reinterpret_cast<const float4*>(inC + iy*WI);
      #pragma unroll
      for (int j=0;j<WI/4;j++){ float4 q=rp[j]; raw[4*j]=q.x; raw[4*j+1]=q.y; raw[4*j+2]=q.z; raw[4*j+3]=q.w; }
      if constexpr (BN_IN){
        #pragma unroll
        for (int j=0;j<WI;j++){ float x = raw[j]*sc + sh; raw[j] = x > 0.f ? x : 0.2f*x; }
      }
      const float4 wq = *reinterpret_cast<const float4*>(w + (((size_t)co*CI + ci)*4 + ky)*4);
      const float wk[4] = {wq.x, wq.y, wq.z, wq.w};
      #pragma unroll
      for (int kx=0;kx<4;kx++){
        #pragma unroll
        for (int ox=0;ox<WO;ox++){
          const int ix = ox*2 - 1 + kx;
          if (ix >= 0 && ix < WI) acc[ox] += raw[ix]*wk[kx];
        }
      }
    }
  }
  const float bv = bias[co];
  #pragma unroll
  for (int ox=0;ox<WO;ox++){
    out[(((size_t)n*CO + co)*HO + oy)*WO + ox] = acc[ox] + bv;
  }
}

// ---------------------------------------------------------------------------
// training-mode BN statistics -> per-channel scale/shift
// ---------------------------------------------------------------------------
template<int CO, int PX>
__global__ __launch_bounds__(256) void k_bnstats(const float* __restrict__ z,
    const float* __restrict__ g, const float* __restrict__ be,
    float* __restrict__ scale, float* __restrict__ shift){
  const int c = blockIdx.x, t = threadIdx.x;
  double s = 0.0, q = 0.0;
  for (int i=t; i<NPATCH*PX; i+=256){
    const int n = i / PX, p = i % PX;
    const float x = z[((size_t)n*CO + c)*PX + p];
    s += (double)x; q += (double)x*(double)x;
  }
  #pragma unroll
  for (int o=32;o>=1;o>>=1){ s += __shfl_down(s,o); q += __shfl_down(q,o); }
  __shared__ double ls[4], lq[4];
  if ((t & 63) == 0){ ls[t>>6] = s; lq[t>>6] = q; }
  __syncthreads();
  if (t==0){
    const double S = ls[0]+ls[1]+ls[2]+ls[3];
    const double Q = lq[0]+lq[1]+lq[2]+lq[3];
    const double cnt = (double)(NPATCH*PX);
    const double m  = S/cnt;
    const double var = Q/cnt - m*m;
    const float scl = g[c] / sqrtf((float)var + 1e-5f);
    scale[c] = scl;
    shift[c] = be[c] - (float)m*scl;
  }
}

// ---------------------------------------------------------------------------
// conv5: 512 -> 1, 4x4 input, k4 s1 p0 (dot product), BN4+lrelu on input
// ---------------------------------------------------------------------------
__global__ __launch_bounds__(256) void k_conv5(const float* __restrict__ z4,
    const float* __restrict__ scale, const float* __restrict__ shift,
    const float* __restrict__ w5, const float* __restrict__ b5,
    float* __restrict__ logits){
  const int n = blockIdx.x, t = threadIdx.x;
  float part = 0.f;
  for (int k=t; k<8192; k+=256){
    const int ci = k >> 4;
    float x = z4[((size_t)n*512)*16 + k];
    x = x*scale[ci] + shift[ci];
    x = x > 0.f ? x : 0.2f*x;
    part += x * w5[k];
  }
  #pragma unroll
  for (int o=32;o>=1;o>>=1) part += __shfl_down(part, o);
  __shared__ float ls[4];
  if ((t & 63) == 0) ls[t>>6] = part;
  __syncthreads();
  if (t==0) logits[n] = ls[0]+ls[1]+ls[2]+ls[3] + b5[0];
}

// ---------------------------------------------------------------------------
// loss = mean(softplus(-logit)) over 64 patches
// ---------------------------------------------------------------------------
__global__ void k_loss(const float* __restrict__ logits, float* __restrict__ out){
  const int t = threadIdx.x;
  float u  = -logits[t];
  float sp = fmaxf(u, 0.f) + log1pf(expf(-fabsf(u)));
  #pragma unroll
  for (int o=32;o>=1;o>>=1) sp += __shfl_down(sp, o);
  if (t==0) out[0] = sp * (1.0f/64.0f);
}

// ---------------------------------------------------------------------------
extern "C" void kernel_launch(void* const* d_in, const int* in_sizes, int n_in,
                              void* d_out, int out_size, void* d_ws, size_t ws_size,
                              hipStream_t stream) {
  const float* pred     = (const float*)d_in[0];
  const float* source   = (const float*)d_in[1];
  const int*   rand_sel = (const int*)  d_in[2];
  const float* w1 = (const float*)d_in[3];  const float* b1 = (const float*)d_in[4];
  const float* w2 = (const float*)d_in[5];  const float* b2 = (const float*)d_in[6];
  const float* g2 = (const float*)d_in[7];  const float* be2= (const float*)d_in[8];
  const float* w3 = (const float*)d_in[9];  const float* b3 = (const float*)d_in[10];
  const float* g3 = (const float*)d_in[11]; const float* be3= (const float*)d_in[12];
  const float* w4 = (const float*)d_in[13]; const float* b4 = (const float*)d_in[14];
  const float* g4 = (const float*)d_in[15]; const float* be4= (const float*)d_in[16];
  const float* w5 = (const float*)d_in[17]; const float* b5 = (const float*)d_in[18];

  float* ws = (float*)d_ws;
  // --- zero-initialized region (contiguous) ---
  unsigned* hist  = (unsigned*)ws;          // 16*2048
  unsigned* hist2 = hist + 16*2048;         // 16*8192
  unsigned* cntb  = hist2 + 16*8192;        // 16
  int*      flag  = (int*)(cntb + 16);      // 16
  const int ZTOT  = 16*2048 + 16*8192 + 16 + 16;   // u32 count
  size_t o = (size_t)ZTOT;
  int2*     tinfo = (int2*)(ws + o);        o += 32;
  unsigned* thr   = (unsigned*)(ws + o);    o += 16;
  // o is even here -> 8-byte aligned for cand
  unsigned long long* cand = (unsigned long long*)(ws + o); o += (size_t)16*2048*2;
  float* maskbuf = ws + o;              o += (size_t)B_*HW_;   // mask, later window
  float* rowsum  = ws + o;              o += (size_t)B_*HW_;
  int*   coords  = (int*)(ws + o);      o += 128;
  float* patches = ws + o;              o += (size_t)NPATCH*3*64*64;
  float* a1      = ws + o;              o += (size_t)NPATCH*64*32*32;
  float* z2      = ws + o;              o += (size_t)NPATCH*128*16*16;
  float* z3      = ws + o;              o += (size_t)NPATCH*256*8*8;
  float* z4      = ws + o;              o += (size_t)NPATCH*512*4*4;
  float* scale2  = ws + o;              o += 128;
  float* shift2  = ws + o;              o += 128;
  float* scale3  = ws + o;              o += 256;
  float* shift3  = ws + o;              o += 256;
  float* scale4  = ws + o;              o += 512;
  float* shift4  = ws + o;              o += 512;
  float* logits  = ws + o;              o += 64;
  (void)ws_size; (void)in_sizes; (void)n_in; (void)out_size;

  const int npix = B_*HW_;
  const int pixBlocks = (npix + 255)/256;

  k_zero<<<(ZTOT + 255)/256, 256, 0, stream>>>(hist, ZTOT);
  k_flag<<<2048, 256, 0, stream>>>((const float4*)source, (B_*3*HW_)/4, flag);
  k_detector<<<pixBlocks, 256, 0, stream>>>(source, flag, maskbuf);
  k_box_row<<<pixBlocks, 256, 0, stream>>>(maskbuf, rowsum);
  k_box_col<<<pixBlocks, 256, 0, stream>>>(rowsum, maskbuf);   // window overwrites mask

  k_hist   <<<16*16, 256, 0, stream>>>(maskbuf, hist);
  k_thresh_a<<<16, 256, 0, stream>>>(hist, tinfo);
  k_hist2  <<<16*16, 256, 0, stream>>>(maskbuf, tinfo, hist2);
  k_thresh_b<<<16, 256, 0, stream>>>(hist2, tinfo, thr);
  k_collect<<<16*16, 256, 0, stream>>>(maskbuf, thr, cand, cntb);
  k_sort   <<<16, 1024, 0, stream>>>(cand, cntb, rand_sel, coords);

  k_patch<<<(NPATCH*3*64*64 + 255)/256, 256, 0, stream>>>(pred, coords, patches);

  k_conv1<<<(NPATCH*64*32 + 255)/256, 256, 0, stream>>>(patches, w1, b1, a1);

  k_conv_s2<64, 128, 32, false><<<(NPATCH*128*16 + 255)/256, 256, 0, stream>>>(
      a1, w2, b2, nullptr, nullptr, z2);
  k_bnstats<128, 256><<<128, 256, 0, stream>>>(z2, g2, be2, scale2, shift2);

  k_conv_s2<128, 256, 16, true><<<(NPATCH*256*8 + 255)/256, 256, 0, stream>>>(
      z2, w3, b3, scale2, shift2, z3);
  k_bnstats<256, 64><<<256, 256, 0, stream>>>(z3, g3, be3, scale3, shift3);

  k_conv_s2<256, 512, 8, true><<<(NPATCH*512*4 + 255)/256, 256, 0, stream>>>(
      z3, w4, b4, scale3, shift3, z4);
  k_bnstats<512, 16><<<512, 256, 0, stream>>>(z4, g4, be4, scale4, shift4);

  k_conv5<<<NPATCH, 256, 0, stream>>>(z4, scale4, shift4, w5, b5, logits);
  k_loss<<<1, 64, 0, stream>>>(logits, (float*)d_out);
}

// Round 7
// 1902.754 us; speedup vs baseline: 1.9250x; 1.0177x over previous
//
#include <hip/hip_runtime.h>
#include <hip/hip_bf16.h>

// Problem constants
#define B_    16
#define H_    768
#define W_    768
#define HW_   (H_*W_)        // 589824
#define P_    64
#define NP_   4
#define TOPK_ 100
#define NPATCH (B_*NP_)      // 64 patches

// ---------------------------------------------------------------------------
// zero the histogram/counter region
// ---------------------------------------------------------------------------
__global__ void k_zero(unsigned* __restrict__ p, int n){
  int i = blockIdx.x*blockDim.x + threadIdx.x;
  if (i < n) p[i] = 0u;
}

// ---------------------------------------------------------------------------
// flag = any(source < 0)
// ---------------------------------------------------------------------------
__global__ void k_flag(const float4* __restrict__ s, int n4, int* __restrict__ flag){
  int idx = blockIdx.x*blockDim.x + threadIdx.x;
  int strd = gridDim.x*blockDim.x;
  bool neg = false;
  for (int i=idx; i<n4; i+=strd){
    float4 q = s[i];
    neg = neg || (q.x<0.f) || (q.y<0.f) || (q.z<0.f) || (q.w<0.f);
  }
  if (__any((int)neg)){
    if ((threadIdx.x & 63) == 0) atomicOr(flag, 1);
  }
}

// ---------------------------------------------------------------------------
// detector: mask = sigmoid(20*(brightness-0.65)) * sigmoid(20*(0.15-sat))
// ---------------------------------------------------------------------------
__global__ void k_detector(const float* __restrict__ src, const int* __restrict__ flag,
                           float* __restrict__ mask){
  int i = blockIdx.x*blockDim.x + threadIdx.x;
  if (i >= B_*HW_) return;
  int b = i / HW_;
  int p = i - b*HW_;
  const float* sb = src + (size_t)b*3*HW_;
  float r = sb[p], g = sb[HW_+p], bl = sb[2*HW_+p];
  if (*flag){ r = (r+1.f)*0.5f; g = (g+1.f)*0.5f; bl = (bl+1.f)*0.5f; }
  float br = 0.299f*r + 0.587f*g + 0.114f*bl;
  float bm = 1.f/(1.f + expf(-20.f*(br - 0.65f)));
  float mx = fmaxf(r, fmaxf(g, bl));
  float mn = fminf(r, fminf(g, bl));
  float ls = 1.f/(1.f + expf(-20.f*(0.15f - (mx-mn))));
  mask[i] = bm*ls;
}

// ---------------------------------------------------------------------------
// separable 15x15 box filter (zero pad, divide by 225 at the end)
// ---------------------------------------------------------------------------
__global__ void k_box_row(const float* __restrict__ in, float* __restrict__ out){
  int i = blockIdx.x*blockDim.x + threadIdx.x;
  if (i >= B_*HW_) return;
  int x = i % W_;
  int base = i - x;
  float s = 0.f;
  #pragma unroll
  for (int d=-7; d<=7; ++d){
    int xx = x + d;
    if (xx >= 0 && xx < W_) s += in[base + xx];
  }
  out[i] = s;
}

__global__ void k_box_col(const float* __restrict__ in, float* __restrict__ out){
  int i = blockIdx.x*blockDim.x + threadIdx.x;
  if (i >= B_*HW_) return;
  int p = i % HW_;
  int y = p / W_;
  float s = 0.f;
  #pragma unroll
  for (int d=-7; d<=7; ++d){
    int yy = y + d;
    if (yy >= 0 && yy < H_) s += in[i + d*W_];
  }
  out[i] = s / 225.0f;
}

// ---------------------------------------------------------------------------
// TOP-K stage 1: per-image 2048-bin histogram of valbits>>19 (LDS-privatized)
// ---------------------------------------------------------------------------
__global__ __launch_bounds__(256) void k_hist(const float* __restrict__ win,
                                              unsigned* __restrict__ hist){
  const int img   = blockIdx.x >> 4;
  const int chunk = blockIdx.x & 15;
  __shared__ unsigned lh[2048];
  for (int i=threadIdx.x;i<2048;i+=256) lh[i]=0u;
  __syncthreads();
  const float4* base = reinterpret_cast<const float4*>(win + (size_t)img*HW_ + chunk*36864);
  for (int it=0; it<36; ++it){
    float4 q = base[it*256 + threadIdx.x];
    atomicAdd(&lh[__float_as_uint(q.x) >> 19], 1u);
    atomicAdd(&lh[__float_as_uint(q.y) >> 19], 1u);
    atomicAdd(&lh[__float_as_uint(q.z) >> 19], 1u);
    atomicAdd(&lh[__float_as_uint(q.w) >> 19], 1u);
  }
  __syncthreads();
  unsigned* h = hist + img*2048;
  for (int i=threadIdx.x;i<2048;i+=256){
    unsigned v = lh[i];
    if (v) atomicAdd(&h[i], v);
  }
}

// ---------------------------------------------------------------------------
// TOP-K stage 2: find threshold bin t1 + count strictly above it
// ---------------------------------------------------------------------------
__global__ __launch_bounds__(256) void k_thresh_a(const unsigned* __restrict__ hist,
                                                  int2* __restrict__ tinfo){
  const int img = blockIdx.x;
  __shared__ unsigned h[2048];
  __shared__ unsigned ch[256];
  const int t = threadIdx.x;
  for (int i=t;i<2048;i+=256) h[i] = hist[img*2048+i];
  __syncthreads();
  unsigned s = 0;
  #pragma unroll
  for (int j=0;j<8;j++) s += h[t*8+j];
  ch[t] = s;
  __syncthreads();
  if (t==0){
    unsigned acc = 0; int c = 255;
    for (; c>0; --c){ if (acc + ch[c] >= (unsigned)TOPK_) break; acc += ch[c]; }
    int b = c*8+7;
    for (; b>c*8; --b){ if (acc + h[b] >= (unsigned)TOPK_) break; acc += h[b]; }
    tinfo[img] = make_int2(b, (int)acc);
  }
}

// ---------------------------------------------------------------------------
// TOP-K stage 3: 8192-bin histogram of bits 18..6 for elements in bin t1
// ---------------------------------------------------------------------------
__global__ __launch_bounds__(256) void k_hist2(const float* __restrict__ win,
                                               const int2* __restrict__ tinfo,
                                               unsigned* __restrict__ hist2){
  const int img   = blockIdx.x >> 4;
  const int chunk = blockIdx.x & 15;
  const unsigned t1 = (unsigned)tinfo[img].x;
  __shared__ unsigned lh[8192];
  for (int i=threadIdx.x;i<8192;i+=256) lh[i]=0u;
  __syncthreads();
  const float4* base = reinterpret_cast<const float4*>(win + (size_t)img*HW_ + chunk*36864);
  for (int it=0; it<36; ++it){
    float4 q = base[it*256 + threadIdx.x];
    float vv[4] = {q.x, q.y, q.z, q.w};
    #pragma unroll
    for (int c=0;c<4;c++){
      unsigned vb = __float_as_uint(vv[c]);
      if ((vb >> 19) == t1) atomicAdd(&lh[(vb >> 6) & 8191u], 1u);
    }
  }
  __syncthreads();
  unsigned* h = hist2 + img*8192;
  for (int i=threadIdx.x;i<8192;i+=256){
    unsigned v = lh[i];
    if (v) atomicAdd(&h[i], v);
  }
}

// ---------------------------------------------------------------------------
// TOP-K stage 4: final 26-bit threshold T
// ---------------------------------------------------------------------------
__global__ __launch_bounds__(256) void k_thresh_b(const unsigned* __restrict__ hist2,
                                                  const int2* __restrict__ tinfo,
                                                  unsigned* __restrict__ thr){
  const int img = blockIdx.x;
  __shared__ unsigned h[8192];
  __shared__ unsigned ch[256];
  const int t = threadIdx.x;
  for (int i=t;i<8192;i+=256) h[i] = hist2[img*8192+i];
  __syncthreads();
  unsigned s = 0;
  #pragma unroll
  for (int j=0;j<32;j++) s += h[t*32+j];
  ch[t] = s;
  __syncthreads();
  if (t==0){
    unsigned acc = (unsigned)tinfo[img].y;
    int c = 255;
    for (; c>0; --c){ if (acc + ch[c] >= (unsigned)TOPK_) break; acc += ch[c]; }
    int b = c*32+31;
    for (; b>c*32; --b){ if (acc + h[b] >= (unsigned)TOPK_) break; acc += h[b]; }
    thr[img] = (((unsigned)tinfo[img].x) << 19) | ((unsigned)b << 6);
  }
}

// ---------------------------------------------------------------------------
// TOP-K stage 5: compact all elements with valbits >= T into 64-bit keys
// ---------------------------------------------------------------------------
__global__ __launch_bounds__(256) void k_collect(const float* __restrict__ win,
                                                 const unsigned* __restrict__ thr,
                                                 unsigned long long* __restrict__ cand,
                                                 unsigned* __restrict__ cnt){
  const int img   = blockIdx.x >> 4;
  const int chunk = blockIdx.x & 15;
  const unsigned T = thr[img];
  const float4* base = reinterpret_cast<const float4*>(win + (size_t)img*HW_ + chunk*36864);
  unsigned long long* cimg = cand + (size_t)img*2048;
  const int lane = threadIdx.x & 63;
  for (int it=0; it<36; ++it){
    float4 q = base[it*256 + threadIdx.x];
    float vv[4] = {q.x, q.y, q.z, q.w};
    #pragma unroll
    for (int c=0;c<4;c++){
      unsigned vb = __float_as_uint(vv[c]);
      bool take = (vb >= T);
      unsigned long long m = __ballot(take);
      if (m){
        int leader = __builtin_ctzll(m);
        unsigned bs = 0;
        if (lane == leader) bs = atomicAdd(&cnt[img], (unsigned)__popcll(m));
        bs = __shfl(bs, leader);
        if (take){
          unsigned off  = (unsigned)__popcll(m & ((1ULL << lane) - 1ULL));
          unsigned slot = bs + off;
          if (slot < 2048u){
            unsigned idx = (unsigned)(chunk*36864 + (it*256 + threadIdx.x)*4 + c);
            cimg[slot] = (((unsigned long long)vb) << 32) | (unsigned)(~idx);
          }
        }
      }
    }
  }
}

// ---------------------------------------------------------------------------
// TOP-K stage 6: bitonic sort of up to 2048 keys; emit 4 patch coords/image
// ---------------------------------------------------------------------------
__global__ __launch_bounds__(1024) void k_sort(const unsigned long long* __restrict__ cand,
                                               const unsigned* __restrict__ cnt,
                                               const int* __restrict__ rand_sel,
                                               int* __restrict__ coords){
  const int img = blockIdx.x;
  __shared__ unsigned long long s[2048];
  const int t = threadIdx.x;
  unsigned M = cnt[img]; if (M > 2048u) M = 2048u;
  s[t]        = (t          < (int)M) ? cand[(size_t)img*2048 + t]        : 0ULL;
  s[t+1024]   = (t+1024     < (int)M) ? cand[(size_t)img*2048 + t + 1024] : 0ULL;
  for (unsigned k=2; k<=2048u; k<<=1){
    for (unsigned j=k>>1; j>0; j>>=1){
      __syncthreads();
      unsigned i = (((unsigned)t & ~(j-1u)) << 1) | ((unsigned)t & (j-1u));
      unsigned l = i | j;
      unsigned long long a = s[i], b = s[l];
      bool up = ((i & k) == 0u);
      if ((a > b) == up){ s[i] = b; s[l] = a; }
    }
  }
  __syncthreads();
  if (t < NP_){
    int rs = rand_sel[img*NP_ + t];
    rs = rs<0?0:(rs>99?99:rs);
    unsigned long long key = s[2047 - rs];
    unsigned idx = ~((unsigned)(key & 0xFFFFFFFFull));
    int rr = (int)(idx / (unsigned)W_);
    int cc = (int)(idx % (unsigned)W_);
    int y = rr - P_/2; y = y<0?0:(y>(H_-P_)?(H_-P_):y);
    int x = cc - P_/2; x = x<0?0:(x>(W_-P_)?(W_-P_):x);
    coords[(img*NP_+t)*2]   = y;
    coords[(img*NP_+t)*2+1] = x;
  }
}

// ---------------------------------------------------------------------------
// gather 64 patches of (3,64,64) from pred
// ---------------------------------------------------------------------------
__global__ void k_patch(const float* __restrict__ pred, const int* __restrict__ coords,
                        float* __restrict__ patches){
  int i = blockIdx.x*blockDim.x + threadIdx.x;
  if (i >= NPATCH*3*P_*P_) return;
  int x  = i & 63;
  int y  = (i >> 6) & 63;
  int c  = (i >> 12) % 3;
  int bp = i / (3*P_*P_);
  int b  = bp >> 2;
  int py = coords[bp*2], px = coords[bp*2+1];
  patches[i] = pred[(((size_t)b*3 + c)*H_ + (py+y))*W_ + (px+x)];
}

// ---------------------------------------------------------------------------
// conv1: 3->64, 64x64 -> 32x32, k4 s2 p1, bias+lrelu at store.
// one thread per (half, n, co, oy): 16 output columns -> 1024 blocks (4/CU)
// ---------------------------------------------------------------------------
__global__ __launch_bounds__(256) void k_conv1(const float* __restrict__ in,
    const float* __restrict__ w, const float* __restrict__ bias, float* __restrict__ out){
  int id = blockIdx.x*256 + threadIdx.x;
  const int oy   = id % 32;
  const int co   = (id/32) % 64;
  const int n    = (id/(32*64)) % NPATCH;
  const int half = id/(32*64*NPATCH);
  float acc[16];
  #pragma unroll
  for (int o=0;o<16;o++) acc[o]=0.f;
  const float* inN = in + (size_t)n*3*4096;
  const int cstart = half*28;
  #pragma unroll
  for (int ci=0;ci<3;ci++){
    #pragma unroll
    for (int ky=0;ky<4;ky++){
      const int iy = oy*2 - 1 + ky;
      if (iy < 0 || iy >= 64) continue;
      float raw[36];
      const float4* rp = reinterpret_cast<const float4*>(inN + ci*4096 + iy*64 + cstart);
      #pragma unroll
      for (int j=0;j<9;j++){ float4 q=rp[j]; raw[4*j]=q.x; raw[4*j+1]=q.y; raw[4*j+2]=q.z; raw[4*j+3]=q.w; }
      const float4 wq = *reinterpret_cast<const float4*>(w + ((co*3+ci)*4+ky)*4);
      const float wk[4] = {wq.x, wq.y, wq.z, wq.w};
      if (half == 0){
        #pragma unroll
        for (int kx=0;kx<4;kx++){
          #pragma unroll
          for (int ox=0;ox<16;ox++){
            const int ix = ox*2 - 1 + kx;          // [-1, 33]
            if (ix >= 0) acc[ox] += raw[ix]*wk[kx];
          }
        }
      } else {
        #pragma unroll
        for (int kx=0;kx<4;kx++){
          #pragma unroll
          for (int ox=0;ox<16;ox++){
            const int rel = 2*ox + kx + 3;         // ix-28, ix in [31,64]
            if (rel < 36) acc[ox] += raw[rel]*wk[kx];
          }
        }
      }
    }
  }
  const float bv = bias[co];
  float* op = out + (((size_t)n*64 + co)*32 + oy)*32 + half*16;
  #pragma unroll
  for (int ox=0;ox<16;ox++){
    float u = acc[ox] + bv;
    op[ox] = u > 0.f ? u : 0.2f*u;
  }
}

// ---------------------------------------------------------------------------
// split-K direct conv (s2/p1/k4), NO BN (input is pre-activated).
// thread = (s, n, co, oy); writes partial sums part[id*WO + ox].
// ---------------------------------------------------------------------------
template<int CI, int CO, int HI, int NSPLIT>
__global__ __launch_bounds__(256) void k_conv_part(const float* __restrict__ in,
    const float* __restrict__ w, float* __restrict__ part){
  constexpr int HO = HI/2, WI = HI, WO = HI/2, CIS = CI/NSPLIT;
  int id = blockIdx.x*256 + threadIdx.x;
  const int oy = id % HO;
  const int co = (id/HO) % CO;
  const int n  = (id/(HO*CO)) % NPATCH;
  const int s  = id/(HO*CO*NPATCH);
  float acc[WO];
  #pragma unroll
  for (int o=0;o<WO;o++) acc[o]=0.f;
  const float* inN = in + ((size_t)n*CI + s*CIS)*HI*WI;
  const float* wB  = w + ((size_t)co*CI + s*CIS)*16;
  for (int ci=0; ci<CIS; ++ci){
    const float* inC = inN + ci*HI*WI;
    #pragma unroll
    for (int ky=0;ky<4;ky++){
      const int iy = oy*2 - 1 + ky;
      if (iy < 0 || iy >= HI) continue;
      float raw[WI];
      const float4* rp = reinterpret_cast<const float4*>(inC + iy*WI);
      #pragma unroll
      for (int j=0;j<WI/4;j++){ float4 q=rp[j]; raw[4*j]=q.x; raw[4*j+1]=q.y; raw[4*j+2]=q.z; raw[4*j+3]=q.w; }
      const float4 wq = *reinterpret_cast<const float4*>(wB + ci*16 + ky*4);
      const float wk[4] = {wq.x, wq.y, wq.z, wq.w};
      #pragma unroll
      for (int kx=0;kx<4;kx++){
        #pragma unroll
        for (int ox=0;ox<WO;ox++){
          const int ix = ox*2 - 1 + kx;
          if (ix >= 0 && ix < WI) acc[ox] += raw[ix]*wk[kx];
        }
      }
    }
  }
  float* op = part + (size_t)id*WO;
  #pragma unroll
  for (int ox=0;ox<WO;ox++) op[ox] = acc[ox];
}

// ---------------------------------------------------------------------------
// reduce the NSPLIT partials + bias -> z  (float4)
// ---------------------------------------------------------------------------
template<int NSPLIT>
__global__ void k_reduce(const float* __restrict__ part, const float* __restrict__ bias,
                         float* __restrict__ out, int tot4, int per_co, int nco){
  int i = blockIdx.x*blockDim.x + threadIdx.x;
  if (i >= tot4) return;
  const float4* p = reinterpret_cast<const float4*>(part);
  float4 a = p[i];
  #pragma unroll
  for (int s2=1;s2<NSPLIT;s2++){
    float4 b = p[i + (size_t)s2*tot4];
    a.x+=b.x; a.y+=b.y; a.z+=b.z; a.w+=b.w;
  }
  int co = ((i*4)/per_co) % nco;
  float bv = bias[co];
  reinterpret_cast<float4*>(out)[i] = make_float4(a.x+bv, a.y+bv, a.z+bv, a.w+bv);
}

// ---------------------------------------------------------------------------
// elementwise BN(scale,shift)+lrelu: a = lrelu(z*scale[c]+shift[c])
// ---------------------------------------------------------------------------
__global__ void k_bnapply(const float* __restrict__ z, const float* __restrict__ scale,
                          const float* __restrict__ shift, float* __restrict__ out,
                          int tot4, int per_co, int nco){
  int i = blockIdx.x*blockDim.x + threadIdx.x;
  if (i >= tot4) return;
  float4 q = reinterpret_cast<const float4*>(z)[i];
  int co = ((i*4)/per_co) % nco;
  float sc = scale[co], sh = shift[co];
  float v[4] = {q.x,q.y,q.z,q.w};
  #pragma unroll
  for (int j=0;j<4;j++){ float x = v[j]*sc + sh; v[j] = x>0.f?x:0.2f*x; }
  reinterpret_cast<float4*>(out)[i] = make_float4(v[0],v[1],v[2],v[3]);
}

// ---------------------------------------------------------------------------
// training-mode BN statistics -> per-channel scale/shift
// ---------------------------------------------------------------------------
template<int CO, int PX>
__global__ __launch_bounds__(256) void k_bnstats(const float* __restrict__ z,
    const float* __restrict__ g, const float* __restrict__ be,
    float* __restrict__ scale, float* __restrict__ shift){
  const int c = blockIdx.x, t = threadIdx.x;
  double s = 0.0, q = 0.0;
  for (int i=t; i<NPATCH*PX; i+=256){
    const int n = i / PX, p = i % PX;
    const float x = z[((size_t)n*CO + c)*PX + p];
    s += (double)x; q += (double)x*(double)x;
  }
  #pragma unroll
  for (int o=32;o>=1;o>>=1){ s += __shfl_down(s,o); q += __shfl_down(q,o); }
  __shared__ double ls[4], lq[4];
  if ((t & 63) == 0){ ls[t>>6] = s; lq[t>>6] = q; }
  __syncthreads();
  if (t==0){
    const double S = ls[0]+ls[1]+ls[2]+ls[3];
    const double Q = lq[0]+lq[1]+lq[2]+lq[3];
    const double cnt = (double)(NPATCH*PX);
    const double m  = S/cnt;
    const double var = Q/cnt - m*m;
    const float scl = g[c] / sqrtf((float)var + 1e-5f);
    scale[c] = scl;
    shift[c] = be[c] - (float)m*scl;
  }
}

// ---------------------------------------------------------------------------
// conv5: 512 -> 1, 4x4 input, k4 s1 p0 (dot product), BN4+lrelu on input
// ---------------------------------------------------------------------------
__global__ __launch_bounds__(256) void k_conv5(const float* __restrict__ z4,
    const float* __restrict__ scale, const float* __restrict__ shift,
    const float* __restrict__ w5, const float* __restrict__ b5,
    float* __restrict__ logits){
  const int n = blockIdx.x, t = threadIdx.x;
  float part = 0.f;
  for (int k=t; k<8192; k+=256){
    const int ci = k >> 4;
    float x = z4[((size_t)n*512)*16 + k];
    x = x*scale[ci] + shift[ci];
    x = x > 0.f ? x : 0.2f*x;
    part += x * w5[k];
  }
  #pragma unroll
  for (int o=32;o>=1;o>>=1) part += __shfl_down(part, o);
  __shared__ float ls[4];
  if ((t & 63) == 0) ls[t>>6] = part;
  __syncthreads();
  if (t==0) logits[n] = ls[0]+ls[1]+ls[2]+ls[3] + b5[0];
}

// ---------------------------------------------------------------------------
// loss = mean(softplus(-logit)) over 64 patches
// ---------------------------------------------------------------------------
__global__ void k_loss(const float* __restrict__ logits, float* __restrict__ out){
  const int t = threadIdx.x;
  float u  = -logits[t];
  float sp = fmaxf(u, 0.f) + log1pf(expf(-fabsf(u)));
  #pragma unroll
  for (int o=32;o>=1;o>>=1) sp += __shfl_down(sp, o);
  if (t==0) out[0] = sp * (1.0f/64.0f);
}

// ---------------------------------------------------------------------------
extern "C" void kernel_launch(void* const* d_in, const int* in_sizes, int n_in,
                              void* d_out, int out_size, void* d_ws, size_t ws_size,
                              hipStream_t stream) {
  const float* pred     = (const float*)d_in[0];
  const float* source   = (const float*)d_in[1];
  const int*   rand_sel = (const int*)  d_in[2];
  const float* w1 = (const float*)d_in[3];  const float* b1 = (const float*)d_in[4];
  const float* w2 = (const float*)d_in[5];  const float* b2 = (const float*)d_in[6];
  const float* g2 = (const float*)d_in[7];  const float* be2= (const float*)d_in[8];
  const float* w3 = (const float*)d_in[9];  const float* b3 = (const float*)d_in[10];
  const float* g3 = (const float*)d_in[11]; const float* be3= (const float*)d_in[12];
  const float* w4 = (const float*)d_in[13]; const float* b4 = (const float*)d_in[14];
  const float* g4 = (const float*)d_in[15]; const float* be4= (const float*)d_in[16];
  const float* w5 = (const float*)d_in[17]; const float* b5 = (const float*)d_in[18];

  float* ws = (float*)d_ws;
  // --- zero-initialized region (contiguous) ---
  unsigned* hist  = (unsigned*)ws;          // 16*2048
  unsigned* hist2 = hist + 16*2048;         // 16*8192
  unsigned* cntb  = hist2 + 16*8192;        // 16
  int*      flag  = (int*)(cntb + 16);      // 16
  const int ZTOT  = 16*2048 + 16*8192 + 16 + 16;   // u32 count
  size_t o = (size_t)ZTOT;
  int2*     tinfo = (int2*)(ws + o);        o += 32;
  unsigned* thr   = (unsigned*)(ws + o);    o += 16;
  unsigned long long* cand = (unsigned long long*)(ws + o); o += (size_t)16*2048*2;
  float* maskbuf = ws + o;              o += (size_t)B_*HW_;   // mask/window; later conv3 partials
  float* rowsum  = ws + o;              o += (size_t)B_*HW_;   // row sums; later conv2/conv4 partials
  int*   coords  = (int*)(ws + o);      o += 128;
  float* patches = ws + o;              o += (size_t)NPATCH*3*64*64;
  float* a1      = ws + o;              o += (size_t)NPATCH*64*32*32;
  float* z2      = ws + o;              o += (size_t)NPATCH*128*16*16;
  float* a2      = ws + o;              o += (size_t)NPATCH*128*16*16;
  float* z3      = ws + o;              o += (size_t)NPATCH*256*8*8;
  float* a3      = ws + o;              o += (size_t)NPATCH*256*8*8;
  float* z4      = ws + o;              o += (size_t)NPATCH*512*4*4;
  float* scale2  = ws + o;              o += 128;
  float* shift2  = ws + o;              o += 128;
  float* scale3  = ws + o;              o += 256;
  float* shift3  = ws + o;              o += 256;
  float* scale4  = ws + o;              o += 512;
  float* shift4  = ws + o;              o += 512;
  float* logits  = ws + o;              o += 64;
  (void)ws_size; (void)in_sizes; (void)n_in; (void)out_size;

  // partial-sum aliases (lifetimes verified):
  float* part2 = rowsum;    // free after box_col; consumed by reduce2
  float* part3 = maskbuf;   // free after k_collect; consumed by reduce3
  float* part4 = rowsum;    // free after reduce2; consumed by reduce4

  const int npix = B_*HW_;
  const int pixBlocks = (npix + 255)/256;

  k_zero<<<(ZTOT + 255)/256, 256, 0, stream>>>(hist, ZTOT);
  k_flag<<<2048, 256, 0, stream>>>((const float4*)source, (B_*3*HW_)/4, flag);
  k_detector<<<pixBlocks, 256, 0, stream>>>(source, flag, maskbuf);
  k_box_row<<<pixBlocks, 256, 0, stream>>>(maskbuf, rowsum);
  k_box_col<<<pixBlocks, 256, 0, stream>>>(rowsum, maskbuf);

  k_hist   <<<16*16, 256, 0, stream>>>(maskbuf, hist);
  k_thresh_a<<<16, 256, 0, stream>>>(hist, tinfo);
  k_hist2  <<<16*16, 256, 0, stream>>>(maskbuf, tinfo, hist2);
  k_thresh_b<<<16, 256, 0, stream>>>(hist2, tinfo, thr);
  k_collect<<<16*16, 256, 0, stream>>>(maskbuf, thr, cand, cntb);
  k_sort   <<<16, 1024, 0, stream>>>(cand, cntb, rand_sel, coords);

  k_patch<<<(NPATCH*3*64*64 + 255)/256, 256, 0, stream>>>(pred, coords, patches);

  // conv1 (half-rows): 2*64*64*32 threads = 1024 blocks
  k_conv1<<<1024, 256, 0, stream>>>(patches, w1, b1, a1);

  // conv2: 64->128, 32->16, split-K x4 -> 2048 blocks
  k_conv_part<64, 128, 32, 4><<<2048, 256, 0, stream>>>(a1, w2, part2);
  {
    const int tot4 = NPATCH*128*16*16/4;
    k_reduce<4><<<(tot4+255)/256, 256, 0, stream>>>(part2, b2, z2, tot4, 256, 128);
  }
  k_bnstats<128, 256><<<128, 256, 0, stream>>>(z2, g2, be2, scale2, shift2);
  {
    const int tot4 = NPATCH*128*16*16/4;
    k_bnapply<<<(tot4+255)/256, 256, 0, stream>>>(z2, scale2, shift2, a2, tot4, 256, 128);
  }

  // conv3: 128->256, 16->8, split-K x4 -> 2048 blocks
  k_conv_part<128, 256, 16, 4><<<2048, 256, 0, stream>>>(a2, w3, part3);
  {
    const int tot4 = NPATCH*256*8*8/4;
    k_reduce<4><<<(tot4+255)/256, 256, 0, stream>>>(part3, b3, z3, tot4, 64, 256);
  }
  k_bnstats<256, 64><<<256, 256, 0, stream>>>(z3, g3, be3, scale3, shift3);
  {
    const int tot4 = NPATCH*256*8*8/4;
    k_bnapply<<<(tot4+255)/256, 256, 0, stream>>>(z3, scale3, shift3, a3, tot4, 64, 256);
  }

  // conv4: 256->512, 8->4, split-K x4 -> 2048 blocks
  k_conv_part<256, 512, 8, 4><<<2048, 256, 0, stream>>>(a3, w4, part4);
  {
    const int tot4 = NPATCH*512*4*4/4;
    k_reduce<4><<<(tot4+255)/256, 256, 0, stream>>>(part4, b4, z4, tot4, 16, 512);
  }
  k_bnstats<512, 16><<<512, 256, 0, stream>>>(z4, g4, be4, scale4, shift4);

  k_conv5<<<NPATCH, 256, 0, stream>>>(z4, scale4, shift4, w5, b5, logits);
  k_loss<<<1, 64, 0, stream>>>(logits, (float*)d_out);
}

// Round 8
// 1620.948 us; speedup vs baseline: 2.2596x; 1.1739x over previous
//
#include <hip/hip_runtime.h>
#include <hip/hip_bf16.h>

// Problem constants
#define B_    16
#define H_    768
#define W_    768
#define HW_   (H_*W_)        // 589824
#define P_    64
#define NP_   4
#define TOPK_ 100
#define NPATCH (B_*NP_)      // 64 patches

// ---------------------------------------------------------------------------
// zero the histogram/counter region
// ---------------------------------------------------------------------------
__global__ void k_zero(unsigned* __restrict__ p, int n){
  int i = blockIdx.x*blockDim.x + threadIdx.x;
  if (i < n) p[i] = 0u;
}

// ---------------------------------------------------------------------------
// flag = any(source < 0)
// ---------------------------------------------------------------------------
__global__ void k_flag(const float4* __restrict__ s, int n4, int* __restrict__ flag){
  int idx = blockIdx.x*blockDim.x + threadIdx.x;
  int strd = gridDim.x*blockDim.x;
  bool neg = false;
  for (int i=idx; i<n4; i+=strd){
    float4 q = s[i];
    neg = neg || (q.x<0.f) || (q.y<0.f) || (q.z<0.f) || (q.w<0.f);
  }
  if (__any((int)neg)){
    if ((threadIdx.x & 63) == 0) atomicOr(flag, 1);
  }
}

// ---------------------------------------------------------------------------
// detector: mask = sigmoid(20*(brightness-0.65)) * sigmoid(20*(0.15-sat))
// ---------------------------------------------------------------------------
__global__ void k_detector(const float* __restrict__ src, const int* __restrict__ flag,
                           float* __restrict__ mask){
  int i = blockIdx.x*blockDim.x + threadIdx.x;
  if (i >= B_*HW_) return;
  int b = i / HW_;
  int p = i - b*HW_;
  const float* sb = src + (size_t)b*3*HW_;
  float r = sb[p], g = sb[HW_+p], bl = sb[2*HW_+p];
  if (*flag){ r = (r+1.f)*0.5f; g = (g+1.f)*0.5f; bl = (bl+1.f)*0.5f; }
  float br = 0.299f*r + 0.587f*g + 0.114f*bl;
  float bm = 1.f/(1.f + expf(-20.f*(br - 0.65f)));
  float mx = fmaxf(r, fmaxf(g, bl));
  float mn = fminf(r, fminf(g, bl));
  float ls = 1.f/(1.f + expf(-20.f*(0.15f - (mx-mn))));
  mask[i] = bm*ls;
}

// ---------------------------------------------------------------------------
// separable 15x15 box filter (zero pad, divide by 225 at the end)
// ---------------------------------------------------------------------------
__global__ void k_box_row(const float* __restrict__ in, float* __restrict__ out){
  int i = blockIdx.x*blockDim.x + threadIdx.x;
  if (i >= B_*HW_) return;
  int x = i % W_;
  int base = i - x;
  float s = 0.f;
  #pragma unroll
  for (int d=-7; d<=7; ++d){
    int xx = x + d;
    if (xx >= 0 && xx < W_) s += in[base + xx];
  }
  out[i] = s;
}

__global__ void k_box_col(const float* __restrict__ in, float* __restrict__ out){
  int i = blockIdx.x*blockDim.x + threadIdx.x;
  if (i >= B_*HW_) return;
  int p = i % HW_;
  int y = p / W_;
  float s = 0.f;
  #pragma unroll
  for (int d=-7; d<=7; ++d){
    int yy = y + d;
    if (yy >= 0 && yy < H_) s += in[i + d*W_];
  }
  out[i] = s / 225.0f;
}

// ---------------------------------------------------------------------------
// TOP-K stage 1: per-image 2048-bin histogram of valbits>>19 (LDS-privatized)
// ---------------------------------------------------------------------------
__global__ __launch_bounds__(256) void k_hist(const float* __restrict__ win,
                                              unsigned* __restrict__ hist){
  const int img   = blockIdx.x >> 4;
  const int chunk = blockIdx.x & 15;
  __shared__ unsigned lh[2048];
  for (int i=threadIdx.x;i<2048;i+=256) lh[i]=0u;
  __syncthreads();
  const float4* base = reinterpret_cast<const float4*>(win + (size_t)img*HW_ + chunk*36864);
  for (int it=0; it<36; ++it){
    float4 q = base[it*256 + threadIdx.x];
    atomicAdd(&lh[__float_as_uint(q.x) >> 19], 1u);
    atomicAdd(&lh[__float_as_uint(q.y) >> 19], 1u);
    atomicAdd(&lh[__float_as_uint(q.z) >> 19], 1u);
    atomicAdd(&lh[__float_as_uint(q.w) >> 19], 1u);
  }
  __syncthreads();
  unsigned* h = hist + img*2048;
  for (int i=threadIdx.x;i<2048;i+=256){
    unsigned v = lh[i];
    if (v) atomicAdd(&h[i], v);
  }
}

// ---------------------------------------------------------------------------
// TOP-K stage 2: find threshold bin t1 + count strictly above it
// ---------------------------------------------------------------------------
__global__ __launch_bounds__(256) void k_thresh_a(const unsigned* __restrict__ hist,
                                                  int2* __restrict__ tinfo){
  const int img = blockIdx.x;
  __shared__ unsigned h[2048];
  __shared__ unsigned ch[256];
  const int t = threadIdx.x;
  for (int i=t;i<2048;i+=256) h[i] = hist[img*2048+i];
  __syncthreads();
  unsigned s = 0;
  #pragma unroll
  for (int j=0;j<8;j++) s += h[t*8+j];
  ch[t] = s;
  __syncthreads();
  if (t==0){
    unsigned acc = 0; int c = 255;
    for (; c>0; --c){ if (acc + ch[c] >= (unsigned)TOPK_) break; acc += ch[c]; }
    int b = c*8+7;
    for (; b>c*8; --b){ if (acc + h[b] >= (unsigned)TOPK_) break; acc += h[b]; }
    tinfo[img] = make_int2(b, (int)acc);
  }
}

// ---------------------------------------------------------------------------
// TOP-K stage 3: 8192-bin histogram of bits 18..6 for elements in bin t1
// ---------------------------------------------------------------------------
__global__ __launch_bounds__(256) void k_hist2(const float* __restrict__ win,
                                               const int2* __restrict__ tinfo,
                                               unsigned* __restrict__ hist2){
  const int img   = blockIdx.x >> 4;
  const int chunk = blockIdx.x & 15;
  const unsigned t1 = (unsigned)tinfo[img].x;
  __shared__ unsigned lh[8192];
  for (int i=threadIdx.x;i<8192;i+=256) lh[i]=0u;
  __syncthreads();
  const float4* base = reinterpret_cast<const float4*>(win + (size_t)img*HW_ + chunk*36864);
  for (int it=0; it<36; ++it){
    float4 q = base[it*256 + threadIdx.x];
    float vv[4] = {q.x, q.y, q.z, q.w};
    #pragma unroll
    for (int c=0;c<4;c++){
      unsigned vb = __float_as_uint(vv[c]);
      if ((vb >> 19) == t1) atomicAdd(&lh[(vb >> 6) & 8191u], 1u);
    }
  }
  __syncthreads();
  unsigned* h = hist2 + img*8192;
  for (int i=threadIdx.x;i<8192;i+=256){
    unsigned v = lh[i];
    if (v) atomicAdd(&h[i], v);
  }
}

// ---------------------------------------------------------------------------
// TOP-K stage 4: final 26-bit threshold T
// ---------------------------------------------------------------------------
__global__ __launch_bounds__(256) void k_thresh_b(const unsigned* __restrict__ hist2,
                                                  const int2* __restrict__ tinfo,
                                                  unsigned* __restrict__ thr){
  const int img = blockIdx.x;
  __shared__ unsigned h[8192];
  __shared__ unsigned ch[256];
  const int t = threadIdx.x;
  for (int i=t;i<8192;i+=256) h[i] = hist2[img*8192+i];
  __syncthreads();
  unsigned s = 0;
  #pragma unroll
  for (int j=0;j<32;j++) s += h[t*32+j];
  ch[t] = s;
  __syncthreads();
  if (t==0){
    unsigned acc = (unsigned)tinfo[img].y;
    int c = 255;
    for (; c>0; --c){ if (acc + ch[c] >= (unsigned)TOPK_) break; acc += ch[c]; }
    int b = c*32+31;
    for (; b>c*32; --b){ if (acc + h[b] >= (unsigned)TOPK_) break; acc += h[b]; }
    thr[img] = (((unsigned)tinfo[img].x) << 19) | ((unsigned)b << 6);
  }
}

// ---------------------------------------------------------------------------
// TOP-K stage 5: compact all elements with valbits >= T into 64-bit keys
// ---------------------------------------------------------------------------
__global__ __launch_bounds__(256) void k_collect(const float* __restrict__ win,
                                                 const unsigned* __restrict__ thr,
                                                 unsigned long long* __restrict__ cand,
                                                 unsigned* __restrict__ cnt){
  const int img   = blockIdx.x >> 4;
  const int chunk = blockIdx.x & 15;
  const unsigned T = thr[img];
  const float4* base = reinterpret_cast<const float4*>(win + (size_t)img*HW_ + chunk*36864);
  unsigned long long* cimg = cand + (size_t)img*2048;
  const int lane = threadIdx.x & 63;
  for (int it=0; it<36; ++it){
    float4 q = base[it*256 + threadIdx.x];
    float vv[4] = {q.x, q.y, q.z, q.w};
    #pragma unroll
    for (int c=0;c<4;c++){
      unsigned vb = __float_as_uint(vv[c]);
      bool take = (vb >= T);
      unsigned long long m = __ballot(take);
      if (m){
        int leader = __builtin_ctzll(m);
        unsigned bs = 0;
        if (lane == leader) bs = atomicAdd(&cnt[img], (unsigned)__popcll(m));
        bs = __shfl(bs, leader);
        if (take){
          unsigned off  = (unsigned)__popcll(m & ((1ULL << lane) - 1ULL));
          unsigned slot = bs + off;
          if (slot < 2048u){
            unsigned idx = (unsigned)(chunk*36864 + (it*256 + threadIdx.x)*4 + c);
            cimg[slot] = (((unsigned long long)vb) << 32) | (unsigned)(~idx);
          }
        }
      }
    }
  }
}

// ---------------------------------------------------------------------------
// TOP-K stage 6: bitonic sort of up to 2048 keys; emit 4 patch coords/image
// ---------------------------------------------------------------------------
__global__ __launch_bounds__(1024) void k_sort(const unsigned long long* __restrict__ cand,
                                               const unsigned* __restrict__ cnt,
                                               const int* __restrict__ rand_sel,
                                               int* __restrict__ coords){
  const int img = blockIdx.x;
  __shared__ unsigned long long s[2048];
  const int t = threadIdx.x;
  unsigned M = cnt[img]; if (M > 2048u) M = 2048u;
  s[t]        = (t          < (int)M) ? cand[(size_t)img*2048 + t]        : 0ULL;
  s[t+1024]   = (t+1024     < (int)M) ? cand[(size_t)img*2048 + t + 1024] : 0ULL;
  for (unsigned k=2; k<=2048u; k<<=1){
    for (unsigned j=k>>1; j>0; j>>=1){
      __syncthreads();
      unsigned i = (((unsigned)t & ~(j-1u)) << 1) | ((unsigned)t & (j-1u));
      unsigned l = i | j;
      unsigned long long a = s[i], b = s[l];
      bool up = ((i & k) == 0u);
      if ((a > b) == up){ s[i] = b; s[l] = a; }
    }
  }
  __syncthreads();
  if (t < NP_){
    int rs = rand_sel[img*NP_ + t];
    rs = rs<0?0:(rs>99?99:rs);
    unsigned long long key = s[2047 - rs];
    unsigned idx = ~((unsigned)(key & 0xFFFFFFFFull));
    int rr = (int)(idx / (unsigned)W_);
    int cc = (int)(idx % (unsigned)W_);
    int y = rr - P_/2; y = y<0?0:(y>(H_-P_)?(H_-P_):y);
    int x = cc - P_/2; x = x<0?0:(x>(W_-P_)?(W_-P_):x);
    coords[(img*NP_+t)*2]   = y;
    coords[(img*NP_+t)*2+1] = x;
  }
}

// ---------------------------------------------------------------------------
// gather 64 patches of (3,64,64) from pred
// ---------------------------------------------------------------------------
__global__ void k_patch(const float* __restrict__ pred, const int* __restrict__ coords,
                        float* __restrict__ patches){
  int i = blockIdx.x*blockDim.x + threadIdx.x;
  if (i >= NPATCH*3*P_*P_) return;
  int x  = i & 63;
  int y  = (i >> 6) & 63;
  int c  = (i >> 12) % 3;
  int bp = i / (3*P_*P_);
  int b  = bp >> 2;
  int py = coords[bp*2], px = coords[bp*2+1];
  patches[i] = pred[(((size_t)b*3 + c)*H_ + (py+y))*W_ + (px+x)];
}

// ---------------------------------------------------------------------------
// conv1: 3->64, 64x64 -> 32x32, k4 s2 p1, bias+lrelu at store.
// co-FASTEST mapping: wave = 64 co, same (n,oy) -> input loads broadcast.
// ---------------------------------------------------------------------------
__global__ __launch_bounds__(256) void k_conv1(const float* __restrict__ in,
    const float* __restrict__ w, const float* __restrict__ bias, float* __restrict__ out){
  int id = blockIdx.x*256 + threadIdx.x;
  const int co   = id % 64;
  const int oy   = (id/64) % 32;
  const int n    = (id/(64*32)) % NPATCH;
  const int half = id/(64*32*NPATCH);
  float acc[16];
  #pragma unroll
  for (int o=0;o<16;o++) acc[o]=0.f;
  const float* inN = in + (size_t)n*3*4096;
  const int cstart = half*28;
  #pragma unroll
  for (int ci=0;ci<3;ci++){
    #pragma unroll
    for (int ky=0;ky<4;ky++){
      const int iy = oy*2 - 1 + ky;
      if (iy < 0 || iy >= 64) continue;
      float raw[36];
      const float4* rp = reinterpret_cast<const float4*>(inN + ci*4096 + iy*64 + cstart);
      #pragma unroll
      for (int j=0;j<9;j++){ float4 q=rp[j]; raw[4*j]=q.x; raw[4*j+1]=q.y; raw[4*j+2]=q.z; raw[4*j+3]=q.w; }
      const float4 wq = *reinterpret_cast<const float4*>(w + ((co*3+ci)*4+ky)*4);
      const float wk[4] = {wq.x, wq.y, wq.z, wq.w};
      if (half == 0){
        #pragma unroll
        for (int kx=0;kx<4;kx++){
          #pragma unroll
          for (int ox=0;ox<16;ox++){
            const int ix = ox*2 - 1 + kx;          // [-1, 33]
            if (ix >= 0) acc[ox] += raw[ix]*wk[kx];
          }
        }
      } else {
        #pragma unroll
        for (int kx=0;kx<4;kx++){
          #pragma unroll
          for (int ox=0;ox<16;ox++){
            const int rel = 2*ox + kx + 3;         // ix-28, ix in [31,64]
            if (rel < 36) acc[ox] += raw[rel]*wk[kx];
          }
        }
      }
    }
  }
  const float bv = bias[co];
  float* op = out + (((size_t)n*64 + co)*32 + oy)*32 + half*16;
  #pragma unroll
  for (int ox=0;ox<16;ox++){
    float u = acc[ox] + bv;
    op[ox] = u > 0.f ? u : 0.2f*u;
  }
}

// ---------------------------------------------------------------------------
// split-K direct conv (s2/p1/k4), NO BN (input is pre-activated).
// co-FASTEST: thread = (s, n, oy, co); wave shares (n,oy) -> input broadcast.
// partial layout: part[(((s*NPATCH+n)*HO+oy)*CO+co)*WO + ox]
// ---------------------------------------------------------------------------
template<int CI, int CO, int HI, int NSPLIT>
__global__ __launch_bounds__(256) void k_conv_part(const float* __restrict__ in,
    const float* __restrict__ w, float* __restrict__ part){
  constexpr int HO = HI/2, WI = HI, WO = HI/2, CIS = CI/NSPLIT;
  int id = blockIdx.x*256 + threadIdx.x;
  const int co = id % CO;
  const int oy = (id/CO) % HO;
  const int n  = (id/(CO*HO)) % NPATCH;
  const int s  = id/(CO*HO*NPATCH);
  float acc[WO];
  #pragma unroll
  for (int o=0;o<WO;o++) acc[o]=0.f;
  const float* inN = in + ((size_t)n*CI + s*CIS)*HI*WI;
  const float* wB  = w + ((size_t)co*CI + s*CIS)*16;
  for (int ci=0; ci<CIS; ++ci){
    const float* inC = inN + ci*HI*WI;
    #pragma unroll
    for (int ky=0;ky<4;ky++){
      const int iy = oy*2 - 1 + ky;
      if (iy < 0 || iy >= HI) continue;
      float raw[WI];
      const float4* rp = reinterpret_cast<const float4*>(inC + iy*WI);
      #pragma unroll
      for (int j=0;j<WI/4;j++){ float4 q=rp[j]; raw[4*j]=q.x; raw[4*j+1]=q.y; raw[4*j+2]=q.z; raw[4*j+3]=q.w; }
      const float4 wq = *reinterpret_cast<const float4*>(wB + ci*16 + ky*4);
      const float wk[4] = {wq.x, wq.y, wq.z, wq.w};
      #pragma unroll
      for (int kx=0;kx<4;kx++){
        #pragma unroll
        for (int ox=0;ox<WO;ox++){
          const int ix = ox*2 - 1 + kx;
          if (ix >= 0 && ix < WI) acc[ox] += raw[ix]*wk[kx];
        }
      }
    }
  }
  float* op = part + (size_t)(((s*NPATCH+n)*HO+oy)*CO+co)*WO;
  #pragma unroll
  for (int ox=0;ox<WO;ox++) op[ox] = acc[ox];
}

// ---------------------------------------------------------------------------
// transpose-reduce the NSPLIT partials + bias -> z in [n][co][oy][ox] layout
// ---------------------------------------------------------------------------
template<int CO, int HO, int WO, int NSPLIT>
__global__ void k_reduce_t(const float* __restrict__ part, const float* __restrict__ bias,
                           float* __restrict__ out){
  constexpr int W4 = WO/4;
  constexpr int TOT4 = NPATCH*CO*HO*W4;
  int i = blockIdx.x*blockDim.x + threadIdx.x;
  if (i >= TOT4) return;
  const int x4 = i % W4;
  const int oy = (i / W4) % HO;
  const int co = (i / (W4*HO)) % CO;
  const int n  = i / (W4*HO*CO);
  const float4* p = reinterpret_cast<const float4*>(part);
  float4 a = make_float4(0.f,0.f,0.f,0.f);
  #pragma unroll
  for (int s=0; s<NSPLIT; s++){
    float4 b = p[(size_t)(((s*NPATCH+n)*HO+oy)*CO+co)*W4 + x4];
    a.x+=b.x; a.y+=b.y; a.z+=b.z; a.w+=b.w;
  }
  const float bv = bias[co];
  reinterpret_cast<float4*>(out)[i] = make_float4(a.x+bv, a.y+bv, a.z+bv, a.w+bv);
}

// ---------------------------------------------------------------------------
// elementwise BN(scale,shift)+lrelu: a = lrelu(z*scale[c]+shift[c])
// ---------------------------------------------------------------------------
__global__ void k_bnapply(const float* __restrict__ z, const float* __restrict__ scale,
                          const float* __restrict__ shift, float* __restrict__ out,
                          int tot4, int per_co, int nco){
  int i = blockIdx.x*blockDim.x + threadIdx.x;
  if (i >= tot4) return;
  float4 q = reinterpret_cast<const float4*>(z)[i];
  int co = ((i*4)/per_co) % nco;
  float sc = scale[co], sh = shift[co];
  float v[4] = {q.x,q.y,q.z,q.w};
  #pragma unroll
  for (int j=0;j<4;j++){ float x = v[j]*sc + sh; v[j] = x>0.f?x:0.2f*x; }
  reinterpret_cast<float4*>(out)[i] = make_float4(v[0],v[1],v[2],v[3]);
}

// ---------------------------------------------------------------------------
// training-mode BN statistics -> per-channel scale/shift
// ---------------------------------------------------------------------------
template<int CO, int PX>
__global__ __launch_bounds__(256) void k_bnstats(const float* __restrict__ z,
    const float* __restrict__ g, const float* __restrict__ be,
    float* __restrict__ scale, float* __restrict__ shift){
  const int c = blockIdx.x, t = threadIdx.x;
  double s = 0.0, q = 0.0;
  for (int i=t; i<NPATCH*PX; i+=256){
    const int n = i / PX, p = i % PX;
    const float x = z[((size_t)n*CO + c)*PX + p];
    s += (double)x; q += (double)x*(double)x;
  }
  #pragma unroll
  for (int o=32;o>=1;o>>=1){ s += __shfl_down(s,o); q += __shfl_down(q,o); }
  __shared__ double ls[4], lq[4];
  if ((t & 63) == 0){ ls[t>>6] = s; lq[t>>6] = q; }
  __syncthreads();
  if (t==0){
    const double S = ls[0]+ls[1]+ls[2]+ls[3];
    const double Q = lq[0]+lq[1]+lq[2]+lq[3];
    const double cnt = (double)(NPATCH*PX);
    const double m  = S/cnt;
    const double var = Q/cnt - m*m;
    const float scl = g[c] / sqrtf((float)var + 1e-5f);
    scale[c] = scl;
    shift[c] = be[c] - (float)m*scl;
  }
}

// ---------------------------------------------------------------------------
// conv5: 512 -> 1, 4x4 input, k4 s1 p0 (dot product), BN4+lrelu on input
// ---------------------------------------------------------------------------
__global__ __launch_bounds__(256) void k_conv5(const float* __restrict__ z4,
    const float* __restrict__ scale, const float* __restrict__ shift,
    const float* __restrict__ w5, const float* __restrict__ b5,
    float* __restrict__ logits){
  const int n = blockIdx.x, t = threadIdx.x;
  float part = 0.f;
  for (int k=t; k<8192; k+=256){
    const int ci = k >> 4;
    float x = z4[((size_t)n*512)*16 + k];
    x = x*scale[ci] + shift[ci];
    x = x > 0.f ? x : 0.2f*x;
    part += x * w5[k];
  }
  #pragma unroll
  for (int o=32;o>=1;o>>=1) part += __shfl_down(part, o);
  __shared__ float ls[4];
  if ((t & 63) == 0) ls[t>>6] = part;
  __syncthreads();
  if (t==0) logits[n] = ls[0]+ls[1]+ls[2]+ls[3] + b5[0];
}

// ---------------------------------------------------------------------------
// loss = mean(softplus(-logit)) over 64 patches
// ---------------------------------------------------------------------------
__global__ void k_loss(const float* __restrict__ logits, float* __restrict__ out){
  const int t = threadIdx.x;
  float u  = -logits[t];
  float sp = fmaxf(u, 0.f) + log1pf(expf(-fabsf(u)));
  #pragma unroll
  for (int o=32;o>=1;o>>=1) sp += __shfl_down(sp, o);
  if (t==0) out[0] = sp * (1.0f/64.0f);
}

// ---------------------------------------------------------------------------
extern "C" void kernel_launch(void* const* d_in, const int* in_sizes, int n_in,
                              void* d_out, int out_size, void* d_ws, size_t ws_size,
                              hipStream_t stream) {
  const float* pred     = (const float*)d_in[0];
  const float* source   = (const float*)d_in[1];
  const int*   rand_sel = (const int*)  d_in[2];
  const float* w1 = (const float*)d_in[3];  const float* b1 = (const float*)d_in[4];
  const float* w2 = (const float*)d_in[5];  const float* b2 = (const float*)d_in[6];
  const float* g2 = (const float*)d_in[7];  const float* be2= (const float*)d_in[8];
  const float* w3 = (const float*)d_in[9];  const float* b3 = (const float*)d_in[10];
  const float* g3 = (const float*)d_in[11]; const float* be3= (const float*)d_in[12];
  const float* w4 = (const float*)d_in[13]; const float* b4 = (const float*)d_in[14];
  const float* g4 = (const float*)d_in[15]; const float* be4= (const float*)d_in[16];
  const float* w5 = (const float*)d_in[17]; const float* b5 = (const float*)d_in[18];

  float* ws = (float*)d_ws;
  // --- zero-initialized region (contiguous) ---
  unsigned* hist  = (unsigned*)ws;          // 16*2048
  unsigned* hist2 = hist + 16*2048;         // 16*8192
  unsigned* cntb  = hist2 + 16*8192;        // 16
  int*      flag  = (int*)(cntb + 16);      // 16
  const int ZTOT  = 16*2048 + 16*8192 + 16 + 16;   // u32 count
  size_t o = (size_t)ZTOT;
  int2*     tinfo = (int2*)(ws + o);        o += 32;
  unsigned* thr   = (unsigned*)(ws + o);    o += 16;
  unsigned long long* cand = (unsigned long long*)(ws + o); o += (size_t)16*2048*2;
  float* maskbuf = ws + o;              o += (size_t)B_*HW_;   // mask/window; later conv3 partials
  float* rowsum  = ws + o;              o += (size_t)B_*HW_;   // row sums; later conv2/conv4 partials
  int*   coords  = (int*)(ws + o);      o += 128;
  float* patches = ws + o;              o += (size_t)NPATCH*3*64*64;
  float* a1      = ws + o;              o += (size_t)NPATCH*64*32*32;
  float* z2      = ws + o;              o += (size_t)NPATCH*128*16*16;
  float* a2      = ws + o;              o += (size_t)NPATCH*128*16*16;
  float* z3      = ws + o;              o += (size_t)NPATCH*256*8*8;
  float* a3      = ws + o;              o += (size_t)NPATCH*256*8*8;
  float* z4      = ws + o;              o += (size_t)NPATCH*512*4*4;
  float* scale2  = ws + o;              o += 128;
  float* shift2  = ws + o;              o += 128;
  float* scale3  = ws + o;              o += 256;
  float* shift3  = ws + o;              o += 256;
  float* scale4  = ws + o;              o += 512;
  float* shift4  = ws + o;              o += 512;
  float* logits  = ws + o;              o += 64;
  (void)ws_size; (void)in_sizes; (void)n_in; (void)out_size;

  // partial-sum aliases (lifetimes verified):
  float* part2 = rowsum;    // free after box_col; consumed by reduce2
  float* part3 = maskbuf;   // free after k_collect; consumed by reduce3
  float* part4 = rowsum;    // free after reduce2; consumed by reduce4

  const int npix = B_*HW_;
  const int pixBlocks = (npix + 255)/256;

  k_zero<<<(ZTOT + 255)/256, 256, 0, stream>>>(hist, ZTOT);
  k_flag<<<2048, 256, 0, stream>>>((const float4*)source, (B_*3*HW_)/4, flag);
  k_detector<<<pixBlocks, 256, 0, stream>>>(source, flag, maskbuf);
  k_box_row<<<pixBlocks, 256, 0, stream>>>(maskbuf, rowsum);
  k_box_col<<<pixBlocks, 256, 0, stream>>>(rowsum, maskbuf);

  k_hist   <<<16*16, 256, 0, stream>>>(maskbuf, hist);
  k_thresh_a<<<16, 256, 0, stream>>>(hist, tinfo);
  k_hist2  <<<16*16, 256, 0, stream>>>(maskbuf, tinfo, hist2);
  k_thresh_b<<<16, 256, 0, stream>>>(hist2, tinfo, thr);
  k_collect<<<16*16, 256, 0, stream>>>(maskbuf, thr, cand, cntb);
  k_sort   <<<16, 1024, 0, stream>>>(cand, cntb, rand_sel, coords);

  k_patch<<<(NPATCH*3*64*64 + 255)/256, 256, 0, stream>>>(pred, coords, patches);

  // conv1 (co-fastest, half-rows): 2*64*32*64 threads = 1024 blocks
  k_conv1<<<1024, 256, 0, stream>>>(patches, w1, b1, a1);

  // conv2: 64->128, 32->16, split-K x4 -> 2048 blocks
  k_conv_part<64, 128, 32, 4><<<2048, 256, 0, stream>>>(a1, w2, part2);
  {
    const int tot4 = NPATCH*128*16*16/4;
    k_reduce_t<128, 16, 16, 4><<<(tot4+255)/256, 256, 0, stream>>>(part2, b2, z2);
    k_bnstats<128, 256><<<128, 256, 0, stream>>>(z2, g2, be2, scale2, shift2);
    k_bnapply<<<(tot4+255)/256, 256, 0, stream>>>(z2, scale2, shift2, a2, tot4, 256, 128);
  }

  // conv3: 128->256, 16->8, split-K x4 -> 2048 blocks
  k_conv_part<128, 256, 16, 4><<<2048, 256, 0, stream>>>(a2, w3, part3);
  {
    const int tot4 = NPATCH*256*8*8/4;
    k_reduce_t<256, 8, 8, 4><<<(tot4+255)/256, 256, 0, stream>>>(part3, b3, z3);
    k_bnstats<256, 64><<<256, 256, 0, stream>>>(z3, g3, be3, scale3, shift3);
    k_bnapply<<<(tot4+255)/256, 256, 0, stream>>>(z3, scale3, shift3, a3, tot4, 64, 256);
  }

  // conv4: 256->512, 8->4, split-K x4 -> 2048 blocks
  k_conv_part<256, 512, 8, 4><<<2048, 256, 0, stream>>>(a3, w4, part4);
  {
    const int tot4 = NPATCH*512*4*4/4;
    k_reduce_t<512, 4, 4, 4><<<(tot4+255)/256, 256, 0, stream>>>(part4, b4, z4);
    k_bnstats<512, 16><<<512, 256, 0, stream>>>(z4, g4, be4, scale4, shift4);
  }

  k_conv5<<<NPATCH, 256, 0, stream>>>(z4, scale4, shift4, w5, b5, logits);
  k_loss<<<1, 64, 0, stream>>>(logits, (float*)d_out);
}

// Round 10
// 1209.628 us; speedup vs baseline: 3.0280x; 1.3400x over previous
//
#include <hip/hip_runtime.h>
#include <hip/hip_bf16.h>

// Problem constants
#define B_    16
#define H_    768
#define W_    768
#define HW_   (H_*W_)        // 589824
#define P_    64
#define NP_   4
#define TOPK_ 100
#define NPATCH (B_*NP_)      // 64 patches

// ---------------------------------------------------------------------------
// zero the histogram/counter region
// ---------------------------------------------------------------------------
__global__ void k_zero(unsigned* __restrict__ p, int n){
  int i = blockIdx.x*blockDim.x + threadIdx.x;
  if (i < n) p[i] = 0u;
}

// ---------------------------------------------------------------------------
// weight transpose: w[CO][CI][4][4] -> wt[CI*4+ky][CO][4]  (read scatter,
// write coalesced; runs once, few µs)
// ---------------------------------------------------------------------------
__global__ void k_wtrans(const float* __restrict__ w, float* __restrict__ wt,
                         int CO, int CI){
  int i = blockIdx.x*blockDim.x + threadIdx.x;
  if (i >= CO*CI*16) return;
  int kx = i & 3;
  int co = (i >> 2) % CO;
  int r  = (i >> 2) / CO;          // r = ci*4 + ky
  wt[i] = w[(((size_t)co*CI + (r >> 2))*4 + (r & 3))*4 + kx];
}

// ---------------------------------------------------------------------------
// flag = any(source < 0)
// ---------------------------------------------------------------------------
__global__ void k_flag(const float4* __restrict__ s, int n4, int* __restrict__ flag){
  int idx = blockIdx.x*blockDim.x + threadIdx.x;
  int strd = gridDim.x*blockDim.x;
  bool neg = false;
  for (int i=idx; i<n4; i+=strd){
    float4 q = s[i];
    neg = neg || (q.x<0.f) || (q.y<0.f) || (q.z<0.f) || (q.w<0.f);
  }
  if (__any((int)neg)){
    if ((threadIdx.x & 63) == 0) atomicOr(flag, 1);
  }
}

// ---------------------------------------------------------------------------
// detector: mask = sigmoid(20*(brightness-0.65)) * sigmoid(20*(0.15-sat))
// ---------------------------------------------------------------------------
__global__ void k_detector(const float* __restrict__ src, const int* __restrict__ flag,
                           float* __restrict__ mask){
  int i = blockIdx.x*blockDim.x + threadIdx.x;
  if (i >= B_*HW_) return;
  int b = i / HW_;
  int p = i - b*HW_;
  const float* sb = src + (size_t)b*3*HW_;
  float r = sb[p], g = sb[HW_+p], bl = sb[2*HW_+p];
  if (*flag){ r = (r+1.f)*0.5f; g = (g+1.f)*0.5f; bl = (bl+1.f)*0.5f; }
  float br = 0.299f*r + 0.587f*g + 0.114f*bl;
  float bm = 1.f/(1.f + expf(-20.f*(br - 0.65f)));
  float mx = fmaxf(r, fmaxf(g, bl));
  float mn = fminf(r, fminf(g, bl));
  float ls = 1.f/(1.f + expf(-20.f*(0.15f - (mx-mn))));
  mask[i] = bm*ls;
}

// ---------------------------------------------------------------------------
// separable 15x15 box filter (zero pad, divide by 225 at the end)
// ---------------------------------------------------------------------------
__global__ void k_box_row(const float* __restrict__ in, float* __restrict__ out){
  int i = blockIdx.x*blockDim.x + threadIdx.x;
  if (i >= B_*HW_) return;
  int x = i % W_;
  int base = i - x;
  float s = 0.f;
  #pragma unroll
  for (int d=-7; d<=7; ++d){
    int xx = x + d;
    if (xx >= 0 && xx < W_) s += in[base + xx];
  }
  out[i] = s;
}

__global__ void k_box_col(const float* __restrict__ in, float* __restrict__ out){
  int i = blockIdx.x*blockDim.x + threadIdx.x;
  if (i >= B_*HW_) return;
  int p = i % HW_;
  int y = p / W_;
  float s = 0.f;
  #pragma unroll
  for (int d=-7; d<=7; ++d){
    int yy = y + d;
    if (yy >= 0 && yy < H_) s += in[i + d*W_];
  }
  out[i] = s / 225.0f;
}

// ---------------------------------------------------------------------------
// TOP-K stage 1: per-image 2048-bin histogram of valbits>>19 (LDS-privatized)
// ---------------------------------------------------------------------------
__global__ __launch_bounds__(256) void k_hist(const float* __restrict__ win,
                                              unsigned* __restrict__ hist){
  const int img   = blockIdx.x >> 4;
  const int chunk = blockIdx.x & 15;
  __shared__ unsigned lh[2048];
  for (int i=threadIdx.x;i<2048;i+=256) lh[i]=0u;
  __syncthreads();
  const float4* base = reinterpret_cast<const float4*>(win + (size_t)img*HW_ + chunk*36864);
  for (int it=0; it<36; ++it){
    float4 q = base[it*256 + threadIdx.x];
    atomicAdd(&lh[__float_as_uint(q.x) >> 19], 1u);
    atomicAdd(&lh[__float_as_uint(q.y) >> 19], 1u);
    atomicAdd(&lh[__float_as_uint(q.z) >> 19], 1u);
    atomicAdd(&lh[__float_as_uint(q.w) >> 19], 1u);
  }
  __syncthreads();
  unsigned* h = hist + img*2048;
  for (int i=threadIdx.x;i<2048;i+=256){
    unsigned v = lh[i];
    if (v) atomicAdd(&h[i], v);
  }
}

// ---------------------------------------------------------------------------
// TOP-K stage 2: find threshold bin t1 + count strictly above it
// ---------------------------------------------------------------------------
__global__ __launch_bounds__(256) void k_thresh_a(const unsigned* __restrict__ hist,
                                                  int2* __restrict__ tinfo){
  const int img = blockIdx.x;
  __shared__ unsigned h[2048];
  __shared__ unsigned ch[256];
  const int t = threadIdx.x;
  for (int i=t;i<2048;i+=256) h[i] = hist[img*2048+i];
  __syncthreads();
  unsigned s = 0;
  #pragma unroll
  for (int j=0;j<8;j++) s += h[t*8+j];
  ch[t] = s;
  __syncthreads();
  if (t==0){
    unsigned acc = 0; int c = 255;
    for (; c>0; --c){ if (acc + ch[c] >= (unsigned)TOPK_) break; acc += ch[c]; }
    int b = c*8+7;
    for (; b>c*8; --b){ if (acc + h[b] >= (unsigned)TOPK_) break; acc += h[b]; }
    tinfo[img] = make_int2(b, (int)acc);
  }
}

// ---------------------------------------------------------------------------
// TOP-K stage 3: 8192-bin histogram of bits 18..6 for elements in bin t1
// ---------------------------------------------------------------------------
__global__ __launch_bounds__(256) void k_hist2(const float* __restrict__ win,
                                               const int2* __restrict__ tinfo,
                                               unsigned* __restrict__ hist2){
  const int img   = blockIdx.x >> 4;
  const int chunk = blockIdx.x & 15;
  const unsigned t1 = (unsigned)tinfo[img].x;
  __shared__ unsigned lh[8192];
  for (int i=threadIdx.x;i<8192;i+=256) lh[i]=0u;
  __syncthreads();
  const float4* base = reinterpret_cast<const float4*>(win + (size_t)img*HW_ + chunk*36864);
  for (int it=0; it<36; ++it){
    float4 q = base[it*256 + threadIdx.x];
    float vv[4] = {q.x, q.y, q.z, q.w};
    #pragma unroll
    for (int c=0;c<4;c++){
      unsigned vb = __float_as_uint(vv[c]);
      if ((vb >> 19) == t1) atomicAdd(&lh[(vb >> 6) & 8191u], 1u);
    }
  }
  __syncthreads();
  unsigned* h = hist2 + img*8192;
  for (int i=threadIdx.x;i<8192;i+=256){
    unsigned v = lh[i];
    if (v) atomicAdd(&h[i], v);
  }
}

// ---------------------------------------------------------------------------
// TOP-K stage 4: final 26-bit threshold T
// ---------------------------------------------------------------------------
__global__ __launch_bounds__(256) void k_thresh_b(const unsigned* __restrict__ hist2,
                                                  const int2* __restrict__ tinfo,
                                                  unsigned* __restrict__ thr){
  const int img = blockIdx.x;
  __shared__ unsigned h[8192];
  __shared__ unsigned ch[256];
  const int t = threadIdx.x;
  for (int i=t;i<8192;i+=256) h[i] = hist2[img*8192+i];
  __syncthreads();
  unsigned s = 0;
  #pragma unroll
  for (int j=0;j<32;j++) s += h[t*32+j];
  ch[t] = s;
  __syncthreads();
  if (t==0){
    unsigned acc = (unsigned)tinfo[img].y;
    int c = 255;
    for (; c>0; --c){ if (acc + ch[c] >= (unsigned)TOPK_) break; acc += ch[c]; }
    int b = c*32+31;
    for (; b>c*32; --b){ if (acc + h[b] >= (unsigned)TOPK_) break; acc += h[b]; }
    thr[img] = (((unsigned)tinfo[img].x) << 19) | ((unsigned)b << 6);
  }
}

// ---------------------------------------------------------------------------
// TOP-K stage 5: compact all elements with valbits >= T into 64-bit keys
// ---------------------------------------------------------------------------
__global__ __launch_bounds__(256) void k_collect(const float* __restrict__ win,
                                                 const unsigned* __restrict__ thr,
                                                 unsigned long long* __restrict__ cand,
                                                 unsigned* __restrict__ cnt){
  const int img   = blockIdx.x >> 4;
  const int chunk = blockIdx.x & 15;
  const unsigned T = thr[img];
  const float4* base = reinterpret_cast<const float4*>(win + (size_t)img*HW_ + chunk*36864);
  unsigned long long* cimg = cand + (size_t)img*2048;
  const int lane = threadIdx.x & 63;
  for (int it=0; it<36; ++it){
    float4 q = base[it*256 + threadIdx.x];
    float vv[4] = {q.x, q.y, q.z, q.w};
    #pragma unroll
    for (int c=0;c<4;c++){
      unsigned vb = __float_as_uint(vv[c]);
      bool take = (vb >= T);
      unsigned long long m = __ballot(take);
      if (m){
        int leader = __builtin_ctzll(m);
        unsigned bs = 0;
        if (lane == leader) bs = atomicAdd(&cnt[img], (unsigned)__popcll(m));
        bs = __shfl(bs, leader);
        if (take){
          unsigned off  = (unsigned)__popcll(m & ((1ULL << lane) - 1ULL));
          unsigned slot = bs + off;
          if (slot < 2048u){
            unsigned idx = (unsigned)(chunk*36864 + (it*256 + threadIdx.x)*4 + c);
            cimg[slot] = (((unsigned long long)vb) << 32) | (unsigned)(~idx);
          }
        }
      }
    }
  }
}

// ---------------------------------------------------------------------------
// TOP-K stage 6: bitonic sort of up to 2048 keys; emit 4 patch coords/image
// ---------------------------------------------------------------------------
__global__ __launch_bounds__(1024) void k_sort(const unsigned long long* __restrict__ cand,
                                               const unsigned* __restrict__ cnt,
                                               const int* __restrict__ rand_sel,
                                               int* __restrict__ coords){
  const int img = blockIdx.x;
  __shared__ unsigned long long s[2048];
  const int t = threadIdx.x;
  unsigned M = cnt[img]; if (M > 2048u) M = 2048u;
  s[t]        = (t          < (int)M) ? cand[(size_t)img*2048 + t]        : 0ULL;
  s[t+1024]   = (t+1024     < (int)M) ? cand[(size_t)img*2048 + t + 1024] : 0ULL;
  for (unsigned k=2; k<=2048u; k<<=1){
    for (unsigned j=k>>1; j>0; j>>=1){
      __syncthreads();
      unsigned i = (((unsigned)t & ~(j-1u)) << 1) | ((unsigned)t & (j-1u));
      unsigned l = i | j;
      unsigned long long a = s[i], b = s[l];
      bool up = ((i & k) == 0u);
      if ((a > b) == up){ s[i] = b; s[l] = a; }
    }
  }
  __syncthreads();
  if (t < NP_){
    int rs = rand_sel[img*NP_ + t];
    rs = rs<0?0:(rs>99?99:rs);
    unsigned long long key = s[2047 - rs];
    unsigned idx = ~((unsigned)(key & 0xFFFFFFFFull));
    int rr = (int)(idx / (unsigned)W_);
    int cc = (int)(idx % (unsigned)W_);
    int y = rr - P_/2; y = y<0?0:(y>(H_-P_)?(H_-P_):y);
    int x = cc - P_/2; x = x<0?0:(x>(W_-P_)?(W_-P_):x);
    coords[(img*NP_+t)*2]   = y;
    coords[(img*NP_+t)*2+1] = x;
  }
}

// ---------------------------------------------------------------------------
// gather 64 patches of (3,64,64) from pred
// ---------------------------------------------------------------------------
__global__ void k_patch(const float* __restrict__ pred, const int* __restrict__ coords,
                        float* __restrict__ patches){
  int i = blockIdx.x*blockDim.x + threadIdx.x;
  if (i >= NPATCH*3*P_*P_) return;
  int x  = i & 63;
  int y  = (i >> 6) & 63;
  int c  = (i >> 12) % 3;
  int bp = i / (3*P_*P_);
  int b  = bp >> 2;
  int py = coords[bp*2], px = coords[bp*2+1];
  patches[i] = pred[(((size_t)b*3 + c)*H_ + (py+y))*W_ + (px+x)];
}

// ---------------------------------------------------------------------------
// conv1: 3->64, 64x64 -> 32x32, k4 s2 p1, bias+lrelu at store.
// co-FASTEST mapping: wave = 64 co, same (n,oy) -> input loads broadcast.
// ---------------------------------------------------------------------------
__global__ __launch_bounds__(256) void k_conv1(const float* __restrict__ in,
    const float* __restrict__ w, const float* __restrict__ bias, float* __restrict__ out){
  int id = blockIdx.x*256 + threadIdx.x;
  const int co   = id % 64;
  const int oy   = (id/64) % 32;
  const int n    = (id/(64*32)) % NPATCH;
  const int half = id/(64*32*NPATCH);
  float acc[16];
  #pragma unroll
  for (int o=0;o<16;o++) acc[o]=0.f;
  const float* inN = in + (size_t)n*3*4096;
  const int cstart = half*28;
  #pragma unroll
  for (int ci=0;ci<3;ci++){
    #pragma unroll
    for (int ky=0;ky<4;ky++){
      const int iy = oy*2 - 1 + ky;
      if (iy < 0 || iy >= 64) continue;
      float raw[36];
      const float4* rp = reinterpret_cast<const float4*>(inN + ci*4096 + iy*64 + cstart);
      #pragma unroll
      for (int j=0;j<9;j++){ float4 q=rp[j]; raw[4*j]=q.x; raw[4*j+1]=q.y; raw[4*j+2]=q.z; raw[4*j+3]=q.w; }
      const float4 wq = *reinterpret_cast<const float4*>(w + ((co*3+ci)*4+ky)*4);
      const float wk[4] = {wq.x, wq.y, wq.z, wq.w};
      if (half == 0){
        #pragma unroll
        for (int kx=0;kx<4;kx++){
          #pragma unroll
          for (int ox=0;ox<16;ox++){
            const int ix = ox*2 - 1 + kx;          // [-1, 33]
            if (ix >= 0) acc[ox] += raw[ix]*wk[kx];
          }
        }
      } else {
        #pragma unroll
        for (int kx=0;kx<4;kx++){
          #pragma unroll
          for (int ox=0;ox<16;ox++){
            const int rel = 2*ox + kx + 3;         // ix-28, ix in [31,64]
            if (rel < 36) acc[ox] += raw[rel]*wk[kx];
          }
        }
      }
    }
  }
  const float bv = bias[co];
  float* op = out + (((size_t)n*64 + co)*32 + oy)*32 + half*16;
  #pragma unroll
  for (int ox=0;ox<16;ox++){
    float u = acc[ox] + bv;
    op[ox] = u > 0.f ? u : 0.2f*u;
  }
}

// ---------------------------------------------------------------------------
// split-K direct conv (s2/p1/k4), transposed weights wt[ci*4+ky][CO][4].
// co-FASTEST: thread = (s, n, oy, co); input loads broadcast, weight loads
// lane-coalesced (consecutive co -> consecutive 16B).
// partial layout: part[(((s*NPATCH+n)*HO+oy)*CO+co)*WO + ox]
// ---------------------------------------------------------------------------
template<int CI, int CO, int HI, int NSPLIT>
__global__ __launch_bounds__(256) void k_conv_part(const float* __restrict__ in,
    const float* __restrict__ wt, float* __restrict__ part){
  constexpr int HO = HI/2, WI = HI, WO = HI/2, CIS = CI/NSPLIT;
  int id = blockIdx.x*256 + threadIdx.x;
  const int co = id % CO;
  const int oy = (id/CO) % HO;
  const int n  = (id/(CO*HO)) % NPATCH;
  const int s  = id/(CO*HO*NPATCH);
  float acc[WO];
  #pragma unroll
  for (int o=0;o<WO;o++) acc[o]=0.f;
  const float* inN = in + ((size_t)n*CI + s*CIS)*HI*WI;
  for (int ci=0; ci<CIS; ++ci){
    const float* inC = inN + ci*HI*WI;
    const int cig = s*CIS + ci;
    #pragma unroll
    for (int ky=0;ky<4;ky++){
      const int iy = oy*2 - 1 + ky;
      if (iy < 0 || iy >= HI) continue;
      float raw[WI];
      const float4* rp = reinterpret_cast<const float4*>(inC + iy*WI);
      #pragma unroll
      for (int j=0;j<WI/4;j++){ float4 q=rp[j]; raw[4*j]=q.x; raw[4*j+1]=q.y; raw[4*j+2]=q.z; raw[4*j+3]=q.w; }
      const float4 wq = *reinterpret_cast<const float4*>(wt + ((size_t)(cig*4+ky)*CO + co)*4);
      const float wk[4] = {wq.x, wq.y, wq.z, wq.w};
      #pragma unroll
      for (int kx=0;kx<4;kx++){
        #pragma unroll
        for (int ox=0;ox<WO;ox++){
          const int ix = ox*2 - 1 + kx;
          if (ix >= 0 && ix < WI) acc[ox] += raw[ix]*wk[kx];
        }
      }
    }
  }
  float* op = part + (size_t)(((s*NPATCH+n)*HO+oy)*CO+co)*WO;
  #pragma unroll
  for (int ox=0;ox<WO;ox++) op[ox] = acc[ox];
}

// ---------------------------------------------------------------------------
// transpose-reduce the NSPLIT partials + bias -> z in [n][co][oy][ox] layout
// ---------------------------------------------------------------------------
template<int CO, int HO, int WO, int NSPLIT>
__global__ void k_reduce_t(const float* __restrict__ part, const float* __restrict__ bias,
                           float* __restrict__ out){
  constexpr int W4 = WO/4;
  constexpr int TOT4 = NPATCH*CO*HO*W4;
  int i = blockIdx.x*blockDim.x + threadIdx.x;
  if (i >= TOT4) return;
  const int x4 = i % W4;
  const int oy = (i / W4) % HO;
  const int co = (i / (W4*HO)) % CO;
  const int n  = i / (W4*HO*CO);
  const float4* p = reinterpret_cast<const float4*>(part);
  float4 a = make_float4(0.f,0.f,0.f,0.f);
  #pragma unroll
  for (int s=0; s<NSPLIT; s++){
    float4 b = p[(size_t)(((s*NPATCH+n)*HO+oy)*CO+co)*W4 + x4];
    a.x+=b.x; a.y+=b.y; a.z+=b.z; a.w+=b.w;
  }
  const float bv = bias[co];
  reinterpret_cast<float4*>(out)[i] = make_float4(a.x+bv, a.y+bv, a.z+bv, a.w+bv);
}

// ---------------------------------------------------------------------------
// elementwise BN(scale,shift)+lrelu: a = lrelu(z*scale[c]+shift[c])
// ---------------------------------------------------------------------------
__global__ void k_bnapply(const float* __restrict__ z, const float* __restrict__ scale,
                          const float* __restrict__ shift, float* __restrict__ out,
                          int tot4, int per_co, int nco){
  int i = blockIdx.x*blockDim.x + threadIdx.x;
  if (i >= tot4) return;
  float4 q = reinterpret_cast<const float4*>(z)[i];
  int co = ((i*4)/per_co) % nco;
  float sc = scale[co], sh = shift[co];
  float v[4] = {q.x,q.y,q.z,q.w};
  #pragma unroll
  for (int j=0;j<4;j++){ float x = v[j]*sc + sh; v[j] = x>0.f?x:0.2f*x; }
  reinterpret_cast<float4*>(out)[i] = make_float4(v[0],v[1],v[2],v[3]);
}

// ---------------------------------------------------------------------------
// training-mode BN statistics -> per-channel scale/shift
// ---------------------------------------------------------------------------
template<int CO, int PX>
__global__ __launch_bounds__(256) void k_bnstats(const float* __restrict__ z,
    const float* __restrict__ g, const float* __restrict__ be,
    float* __restrict__ scale, float* __restrict__ shift){
  const int c = blockIdx.x, t = threadIdx.x;
  double s = 0.0, q = 0.0;
  for (int i=t; i<NPATCH*PX; i+=256){
    const int n = i / PX, p = i % PX;
    const float x = z[((size_t)n*CO + c)*PX + p];
    s += (double)x; q += (double)x*(double)x;
  }
  #pragma unroll
  for (int o=32;o>=1;o>>=1){ s += __shfl_down(s,o); q += __shfl_down(q,o); }
  __shared__ double ls[4], lq[4];
  if ((t & 63) == 0){ ls[t>>6] = s; lq[t>>6] = q; }
  __syncthreads();
  if (t==0){
    const double S = ls[0]+ls[1]+ls[2]+ls[3];
    const double Q = lq[0]+lq[1]+lq[2]+lq[3];
    const double cnt = (double)(NPATCH*PX);
    const double m  = S/cnt;
    const double var = Q/cnt - m*m;
    const float scl = g[c] / sqrtf((float)var + 1e-5f);
    scale[c] = scl;
    shift[c] = be[c] - (float)m*scl;
  }
}

// ---------------------------------------------------------------------------
// conv5: 512 -> 1, 4x4 input, k4 s1 p0 (dot product), BN4+lrelu on input
// ---------------------------------------------------------------------------
__global__ __launch_bounds__(256) void k_conv5(const float* __restrict__ z4,
    const float* __restrict__ scale, const float* __restrict__ shift,
    const float* __restrict__ w5, const float* __restrict__ b5,
    float* __restrict__ logits){
  const int n = blockIdx.x, t = threadIdx.x;
  float part = 0.f;
  for (int k=t; k<8192; k+=256){
    const int ci = k >> 4;
    float x = z4[((size_t)n*512)*16 + k];
    x = x*scale[ci] + shift[ci];
    x = x > 0.f ? x : 0.2f*x;
    part += x * w5[k];
  }
  #pragma unroll
  for (int o=32;o>=1;o>>=1) part += __shfl_down(part, o);
  __shared__ float ls[4];
  if ((t & 63) == 0) ls[t>>6] = part;
  __syncthreads();
  if (t==0) logits[n] = ls[0]+ls[1]+ls[2]+ls[3] + b5[0];
}

// ---------------------------------------------------------------------------
// loss = mean(softplus(-logit)) over 64 patches
// ---------------------------------------------------------------------------
__global__ void k_loss(const float* __restrict__ logits, float* __restrict__ out){
  const int t = threadIdx.x;
  float u  = -logits[t];
  float sp = fmaxf(u, 0.f) + log1pf(expf(-fabsf(u)));
  #pragma unroll
  for (int o=32;o>=1;o>>=1) sp += __shfl_down(sp, o);
  if (t==0) out[0] = sp * (1.0f/64.0f);
}

// ---------------------------------------------------------------------------
extern "C" void kernel_launch(void* const* d_in, const int* in_sizes, int n_in,
                              void* d_out, int out_size, void* d_ws, size_t ws_size,
                              hipStream_t stream) {
  const float* pred     = (const float*)d_in[0];
  const float* source   = (const float*)d_in[1];
  const int*   rand_sel = (const int*)  d_in[2];
  const float* w1 = (const float*)d_in[3];  const float* b1 = (const float*)d_in[4];
  const float* w2 = (const float*)d_in[5];  const float* b2 = (const float*)d_in[6];
  const float* g2 = (const float*)d_in[7];  const float* be2= (const float*)d_in[8];
  const float* w3 = (const float*)d_in[9];  const float* b3 = (const float*)d_in[10];
  const float* g3 = (const float*)d_in[11]; const float* be3= (const float*)d_in[12];
  const float* w4 = (const float*)d_in[13]; const float* b4 = (const float*)d_in[14];
  const float* g4 = (const float*)d_in[15]; const float* be4= (const float*)d_in[16];
  const float* w5 = (const float*)d_in[17]; const float* b5 = (const float*)d_in[18];

  float* ws = (float*)d_ws;
  // --- zero-initialized region (contiguous) ---
  unsigned* hist  = (unsigned*)ws;          // 16*2048
  unsigned* hist2 = hist + 16*2048;         // 16*8192
  unsigned* cntb  = hist2 + 16*8192;        // 16
  int*      flag  = (int*)(cntb + 16);      // 16
  const int ZTOT  = 16*2048 + 16*8192 + 16 + 16;   // u32 count
  size_t o = (size_t)ZTOT;
  int2*     tinfo = (int2*)(ws + o);        o += 32;
  unsigned* thr   = (unsigned*)(ws + o);    o += 16;
  unsigned long long* cand = (unsigned long long*)(ws + o); o += (size_t)16*2048*2;
  float* maskbuf = ws + o;              o += (size_t)B_*HW_;   // mask/window; later conv3 partials
  float* rowsum  = ws + o;              o += (size_t)B_*HW_;   // row sums; later conv2/conv4 partials
  int*   coords  = (int*)(ws + o);      o += 128;
  float* patches = ws + o;              o += (size_t)NPATCH*3*64*64;
  float* a1      = ws + o;              o += (size_t)NPATCH*64*32*32;
  float* z2      = ws + o;              o += (size_t)NPATCH*128*16*16;
  float* a2      = ws + o;              o += (size_t)NPATCH*128*16*16;
  float* z3      = ws + o;              o += (size_t)NPATCH*256*8*8;
  float* a3      = ws + o;              o += (size_t)NPATCH*256*8*8;
  float* z4      = ws + o;              o += (size_t)NPATCH*512*4*4;
  float* wt2     = ws + o;              o += (size_t)128*64*16;    // 128K
  float* wt3     = ws + o;              o += (size_t)256*128*16;   // 512K
  float* wt4     = ws + o;              o += (size_t)512*256*16;   // 2M
  float* scale2  = ws + o;              o += 128;
  float* shift2  = ws + o;              o += 128;
  float* scale3  = ws + o;              o += 256;
  float* shift3  = ws + o;              o += 256;
  float* scale4  = ws + o;              o += 512;
  float* shift4  = ws + o;              o += 512;
  float* logits  = ws + o;              o += 64;
  (void)ws_size; (void)in_sizes; (void)n_in; (void)out_size;

  // partial-sum aliases (lifetimes verified):
  float* part2 = rowsum;    // free after box_col; consumed by reduce2
  float* part3 = maskbuf;   // free after k_collect; consumed by reduce3
  float* part4 = rowsum;    // free after reduce2; consumed by reduce4

  const int npix = B_*HW_;
  const int pixBlocks = (npix + 255)/256;

  k_zero<<<(ZTOT + 255)/256, 256, 0, stream>>>(hist, ZTOT);
  // weight transposes (independent of the image pipeline; run first)
  k_wtrans<<<(128*64*16 + 255)/256, 256, 0, stream>>>(w2, wt2, 128, 64);
  k_wtrans<<<(256*128*16 + 255)/256, 256, 0, stream>>>(w3, wt3, 256, 128);
  k_wtrans<<<(512*256*16 + 255)/256, 256, 0, stream>>>(w4, wt4, 512, 256);

  k_flag<<<2048, 256, 0, stream>>>((const float4*)source, (B_*3*HW_)/4, flag);
  k_detector<<<pixBlocks, 256, 0, stream>>>(source, flag, maskbuf);
  k_box_row<<<pixBlocks, 256, 0, stream>>>(maskbuf, rowsum);
  k_box_col<<<pixBlocks, 256, 0, stream>>>(rowsum, maskbuf);

  k_hist   <<<16*16, 256, 0, stream>>>(maskbuf, hist);
  k_thresh_a<<<16, 256, 0, stream>>>(hist, tinfo);
  k_hist2  <<<16*16, 256, 0, stream>>>(maskbuf, tinfo, hist2);
  k_thresh_b<<<16, 256, 0, stream>>>(hist2, tinfo, thr);
  k_collect<<<16*16, 256, 0, stream>>>(maskbuf, thr, cand, cntb);
  k_sort   <<<16, 1024, 0, stream>>>(cand, cntb, rand_sel, coords);

  k_patch<<<(NPATCH*3*64*64 + 255)/256, 256, 0, stream>>>(pred, coords, patches);

  // conv1 (co-fastest, half-rows): 2*64*32*64 threads = 1024 blocks
  k_conv1<<<1024, 256, 0, stream>>>(patches, w1, b1, a1);

  // conv2: 64->128, 32->16, split-K x4 -> 2048 blocks
  k_conv_part<64, 128, 32, 4><<<2048, 256, 0, stream>>>(a1, wt2, part2);
  {
    const int tot4 = NPATCH*128*16*16/4;
    k_reduce_t<128, 16, 16, 4><<<(tot4+255)/256, 256, 0, stream>>>(part2, b2, z2);
    k_bnstats<128, 256><<<128, 256, 0, stream>>>(z2, g2, be2, scale2, shift2);
    k_bnapply<<<(tot4+255)/256, 256, 0, stream>>>(z2, scale2, shift2, a2, tot4, 256, 128);
  }

  // conv3: 128->256, 16->8, split-K x4 -> 2048 blocks
  k_conv_part<128, 256, 16, 4><<<2048, 256, 0, stream>>>(a2, wt3, part3);
  {
    const int tot4 = NPATCH*256*8*8/4;
    k_reduce_t<256, 8, 8, 4><<<(tot4+255)/256, 256, 0, stream>>>(part3, b3, z3);
    k_bnstats<256, 64><<<256, 256, 0, stream>>>(z3, g3, be3, scale3, shift3);
    k_bnapply<<<(tot4+255)/256, 256, 0, stream>>>(z3, scale3, shift3, a3, tot4, 64, 256);
  }

  // conv4: 256->512, 8->4, split-K x4 -> 2048 blocks
  k_conv_part<256, 512, 8, 4><<<2048, 256, 0, stream>>>(a3, wt4, part4);
  {
    const int tot4 = NPATCH*512*4*4/4;
    k_reduce_t<512, 4, 4, 4><<<(tot4+255)/256, 256, 0, stream>>>(part4, b4, z4);
    k_bnstats<512, 16><<<512, 256, 0, stream>>>(z4, g4, be4, scale4, shift4);
  }

  k_conv5<<<NPATCH, 256, 0, stream>>>(z4, scale4, shift4, w5, b5, logits);
  k_loss<<<1, 64, 0, stream>>>(logits, (float*)d_out);
}